// Round 10
// baseline (576.058 us; speedup 1.0000x reference)
//
#include <hip/hip_runtime.h>
#include <stdint.h>

#define NN 50000   // nodes
#define NE 600000  // edges
#define NG 1000    // graphs
#define AD 64      // input feat
#define HD 128     // hidden
#define OD 256     // output
#define BN_EPS_F 1e-5f
#define INV_N (1.0f / 50000.0f)
#define NB 196     // scan blocks = ceil(NN/256)
#define FILLB 586  // fill tail blocks (4 edges/thread)
#define NCOPY 32   // stats atomic spread
#define CSTRIDE 256            // floats per spread copy (sum[128]+sumsq[128])
#define SREG (256 + NCOPY * CSTRIDE)  // 8448 floats per stat region

typedef __attribute__((ext_vector_type(8))) short  mbf16x8;
typedef __attribute__((ext_vector_type(4))) float  mf32x4;
typedef __attribute__((ext_vector_type(4))) unsigned short mu16x4;
typedef __attribute__((ext_vector_type(4))) unsigned int   mu32x4;

__device__ __forceinline__ float bf2f(unsigned short u) {
    union { unsigned int i; float f; } v; v.i = ((unsigned int)u) << 16; return v.f;
}
__device__ __forceinline__ unsigned short f2bf(float f) {
    union { float f; unsigned int i; } v; v.f = f;
    unsigned int r = v.i + 0x7fffu + ((v.i >> 16) & 1u);  // RNE
    return (unsigned short)(r >> 16);
}
// BN (scale, shift) for column c from compact raw sums
__device__ __forceinline__ void bn_ss(
    const float* __restrict__ stats, const float* __restrict__ gamma,
    const float* __restrict__ beta, int c, float& sc, float& sh)
{
    const float mean = stats[c] * INV_N;
    const float var = fmaxf(stats[128 + c] * INV_N - mean * mean, 0.f);
    const float inv = rsqrtf(var + BN_EPS_F);
    sc = gamma[c] * inv;
    sh = beta[c] - mean * sc;
}

// ---------------------------------------------------------------------------
// Weight pre-convert + transpose: wt[n][k] bf16 from W[k][n] fp32.
// Also zeroes stats regions (6*SREG), counters (8), deg (NN).
// ---------------------------------------------------------------------------
__global__ __launch_bounds__(256) void prew_kernel(
    const float* __restrict__ emb_W, const float* __restrict__ W1,
    const float* __restrict__ W2, unsigned short* __restrict__ wt,
    float* __restrict__ stats, int* __restrict__ scnt, int* __restrict__ deg)
{
    const int t = blockIdx.x * 256 + threadIdx.x;
    if (t < 6 * SREG) stats[t] = 0.f;
    if (t < 8) scnt[t] = 0;
    if (t < NN) deg[t] = 0;
    if (t < 8192) {                    // emb: n=t>>6, k=t&63
        wt[t] = f2bf(emb_W[(t & 63) * 128 + (t >> 6)]);
    } else {
        const int t2 = t - 8192;
        if (t2 >= 6 * 16384) return;
        const int which = t2 >> 14, o = t2 & 16383;
        const int n = o >> 7, k = o & 127;
        const float* src = (which < 3) ? (W1 + (size_t)which * 16384)
                                       : (W2 + (size_t)(which - 3) * 16384);
        wt[t] = f2bf(src[k * 128 + n]);
    }
}

// ---------------------------------------------------------------------------
// GEMM: out_bf16[N,128] = A[N,K] @ Wt^T + bias
// AMODE: 0 = A fp32, 1 = A bf16 plain, 2 = A bf16 with BN(stats_in)+ReLU
// SOUT:  per-column sum/sumsq -> NCOPY spread copies (CSTRIDE apart); last
//        block folds to compact stats_out[0..255] (counter, acquire/release)
// TAIL:  1 = CSR fill tail blocks, 2 = graph-starts tail blocks
// ---------------------------------------------------------------------------
template <int K, int AMODE, bool SOUT, int TAIL>
__global__ __launch_bounds__(256) void gemm_kernel(
    const void* __restrict__ in, const unsigned short* __restrict__ Wt,
    const float* __restrict__ bias, const float* __restrict__ stats_in,
    const float* __restrict__ gamma, const float* __restrict__ beta,
    unsigned short* __restrict__ out, float* __restrict__ stats_out,
    int* __restrict__ counter, int nblocks, int n_rows,
    const int* __restrict__ t_a, int* __restrict__ t_b, int* __restrict__ t_c)
{
    constexpr int TAILB = (TAIL == 1) ? FILLB : (TAIL == 2) ? NB : 0;
    if (TAIL != 0 && (int)blockIdx.x < TAILB) {
        const int t = blockIdx.x * 256 + threadIdx.x;
        if constexpr (TAIL == 1) {
            const int e0 = t * 4;
            if (e0 < NE) {   // NE % 4 == 0
                const int4 rv = *(const int4*)(t_a + e0);
                const int4 cv = *(const int4*)(t_a + NE + e0);
                if ((unsigned)rv.x < NN && (unsigned)cv.x < NN)
                    t_c[atomicAdd(&t_b[rv.x], 1)] = cv.x;
                if ((unsigned)rv.y < NN && (unsigned)cv.y < NN)
                    t_c[atomicAdd(&t_b[rv.y], 1)] = cv.y;
                if ((unsigned)rv.z < NN && (unsigned)cv.z < NN)
                    t_c[atomicAdd(&t_b[rv.z], 1)] = cv.z;
                if ((unsigned)rv.w < NN && (unsigned)cv.w < NN)
                    t_c[atomicAdd(&t_b[rv.w], 1)] = cv.w;
            }
        } else {  // TAIL == 2: graph starts
            if (t < NN) {
                int b = t_a[t];
                int pb = (t == 0) ? -1 : t_a[t - 1];
                if (b > NG - 1) b = NG - 1;
                if (pb > NG - 1) pb = NG - 1;
                for (int g = pb + 1; g <= b; g++) t_b[g] = t;
                if (t == NN - 1)
                    for (int g = b + 1; g <= NG; g++) t_b[g] = NN;
            }
        }
        return;
    }
    const int bid = blockIdx.x - TAILB;

    constexpr int SA = K + 8, SB = K + 8;
    __shared__ unsigned short zs[64 * SA];
    __shared__ unsigned short ws[128 * SB];
    __shared__ float ssl[128], ssh[128];
    __shared__ float lsum[128], lsq[128];
    __shared__ int amlast;

    const int tid = threadIdx.x;
    const int wave = tid >> 6, lane = tid & 63;
    const int row0 = bid * 64;

    if (SOUT && tid < 128) { lsum[tid] = 0.f; lsq[tid] = 0.f; }
    if (AMODE == 2) {
        if (tid < 128) {
            float sc, sh; bn_ss(stats_in, gamma, beta, tid, sc, sh);
            ssl[tid] = sc; ssh[tid] = sh;
        }
        __syncthreads();
    }

    // ---- stage Wt (bf16 [n][k]) -> LDS, 16B vectors ----
    constexpr int NSH = (K == 128) ? 7 : 6;
    for (int i = tid; i < 128 * K / 8; i += 256) {
        const int base = i * 8;
        const int n = base >> NSH, k = base & (K - 1);
        *(mu32x4*)(&ws[n * SB + k]) = *(const mu32x4*)(Wt + base);
    }

    // ---- stage A tile -> LDS ----
    if constexpr (AMODE == 0) {
        const float* src = (const float*)in;
        constexpr int LPR = K / 4;
        for (int i = tid; i < 64 * LPR; i += 256) {
            const int r = i / LPR, c4 = (i % LPR) * 4;
            mf32x4 v = {0.f, 0.f, 0.f, 0.f};
            if (row0 + r < n_rows)
                v = *(const mf32x4*)(src + (size_t)(row0 + r) * K + c4);
            mu16x4 o;
            o[0] = f2bf(v[0]); o[1] = f2bf(v[1]); o[2] = f2bf(v[2]); o[3] = f2bf(v[3]);
            *(mu16x4*)(&zs[r * SA + c4]) = o;
        }
    } else {
        const unsigned short* src = (const unsigned short*)in;
        constexpr int LPR = K / 8;
        float sc[8], sh[8];
        if constexpr (AMODE == 2) {
            const int c8 = (tid % LPR) * 8;
#pragma unroll
            for (int j = 0; j < 8; j++) { sc[j] = ssl[c8 + j]; sh[j] = ssh[c8 + j]; }
        }
        for (int i = tid; i < 64 * LPR; i += 256) {
            const int r = i / LPR, c8 = (i % LPR) * 8;
            mu32x4 v = {0, 0, 0, 0};
            if (row0 + r < n_rows)
                v = *(const mu32x4*)(src + (size_t)(row0 + r) * K + c8);
            if constexpr (AMODE == 2) {
                const unsigned short* u = (const unsigned short*)&v;
                mu16x4 oa, ob;
#pragma unroll
                for (int j = 0; j < 4; j++)
                    oa[j] = f2bf(fmaxf(bf2f(u[j]) * sc[j] + sh[j], 0.f));
#pragma unroll
                for (int j = 0; j < 4; j++)
                    ob[j] = f2bf(fmaxf(bf2f(u[4 + j]) * sc[4 + j] + sh[4 + j], 0.f));
                *(mu16x4*)(&zs[r * SA + c8]) = oa;
                *(mu16x4*)(&zs[r * SA + c8 + 4]) = ob;
            } else {
                *(mu32x4*)(&zs[r * SA + c8]) = v;
            }
        }
    }
    __syncthreads();

    // ---- MFMA ----
    mf32x4 acc[8];
#pragma unroll
    for (int t = 0; t < 8; t++) acc[t] = {0.f, 0.f, 0.f, 0.f};
    const int m = wave * 16 + (lane & 15);
    const int kq = (lane >> 4) * 8;
#pragma unroll
    for (int kk = 0; kk < K / 32; kk++) {
        const int k0 = kk * 32 + kq;
        mbf16x8 a = *(const mbf16x8*)(&zs[m * SA + k0]);
#pragma unroll
        for (int t = 0; t < 8; t++) {
            const int n = t * 16 + (lane & 15);
            mbf16x8 b = *(const mbf16x8*)(&ws[n * SB + k0]);
            acc[t] = __builtin_amdgcn_mfma_f32_16x16x32_bf16(a, b, acc[t], 0, 0, 0);
        }
    }

    // ---- epilogue: +bias, store bf16; fused column stats ----
    const int rbase = wave * 16 + ((lane >> 4) << 2);
#pragma unroll
    for (int t = 0; t < 8; t++) {
        const int c = t * 16 + (lane & 15);
        const float bv = bias[c];
        float s = 0.f, q = 0.f;
#pragma unroll
        for (int r = 0; r < 4; r++) {
            const int grow = row0 + rbase + r;
            const float y = acc[t][r] + bv;
            if (grow < n_rows) {
                out[(size_t)grow * 128 + c] = f2bf(y);
                if (SOUT) { s += y; q += y * y; }
            }
        }
        if (SOUT) {
            s += __shfl_xor(s, 16); s += __shfl_xor(s, 32);
            q += __shfl_xor(q, 16); q += __shfl_xor(q, 32);
            if ((lane >> 4) == 0) {
                atomicAdd(&lsum[c], s);
                atomicAdd(&lsq[c], q);
            }
        }
    }
    if (SOUT) {
        __syncthreads();
        // spread atomics over NCOPY slots (CSTRIDE floats apart)
        float* cb = stats_out + 256 + (bid & (NCOPY - 1)) * CSTRIDE;
        if (tid < 128) {
            atomicAdd(&cb[tid], lsum[tid]);
            atomicAdd(&cb[128 + tid], lsq[tid]);
        }
        __syncthreads();  // drain this block's atomics before signaling
        if (tid == 0) {
            __threadfence();
            const int prev = __hip_atomic_fetch_add(
                counter, 1, __ATOMIC_ACQ_REL, __HIP_MEMORY_SCOPE_AGENT);
            amlast = (prev == nblocks - 1) ? 1 : 0;
        }
        __syncthreads();
        if (amlast && tid < 256) {
            float a = 0.f;
#pragma unroll 8
            for (int c2 = 0; c2 < NCOPY; c2++)
                a += __hip_atomic_load(stats_out + 256 + c2 * CSTRIDE + tid,
                                       __ATOMIC_RELAXED, __HIP_MEMORY_SCOPE_AGENT);
            stats_out[tid] = a;  // compact; consumed by later kernels
        }
    }
}

// ---------------------------------------------------------------------------
// CSR build: histogram (4 edges/thread) -> bscan -> scanfix
// ---------------------------------------------------------------------------
__global__ __launch_bounds__(256) void deg_kernel(
    const int* __restrict__ ei, int* __restrict__ deg)
{
    const int e0 = (blockIdx.x * 256 + threadIdx.x) * 4;
    if (e0 >= NE) return;   // NE % 4 == 0
    const int4 rv = *(const int4*)(ei + e0);
    if ((unsigned)rv.x < NN) atomicAdd(&deg[rv.x], 1);
    if ((unsigned)rv.y < NN) atomicAdd(&deg[rv.y], 1);
    if ((unsigned)rv.z < NN) atomicAdd(&deg[rv.z], 1);
    if ((unsigned)rv.w < NN) atomicAdd(&deg[rv.w], 1);
}

__global__ __launch_bounds__(256) void bscan_kernel(
    const int* __restrict__ deg, int* __restrict__ rowptr, int* __restrict__ bsum)
{
    __shared__ int sm[256];
    const int t = threadIdx.x, idx = blockIdx.x * 256 + t;
    const int d = (idx < NN) ? deg[idx] : 0;
    sm[t] = d; __syncthreads();
    for (int ofs = 1; ofs < 256; ofs <<= 1) {
        int v = (t >= ofs) ? sm[t - ofs] : 0;
        __syncthreads();
        sm[t] += v;
        __syncthreads();
    }
    if (idx < NN) rowptr[idx] = sm[t] - d;  // exclusive, block-local
    if (t == 255) bsum[blockIdx.x] = sm[255];
}

// each block re-scans bsum itself, adds its offset, fills cursor
__global__ __launch_bounds__(256) void scanfix_kernel(
    const int* __restrict__ bsum, int* __restrict__ rowptr, int* __restrict__ cursor)
{
    __shared__ int sm[256];
    const int t = threadIdx.x;
    const int d = (t < NB) ? bsum[t] : 0;
    sm[t] = d; __syncthreads();
    for (int ofs = 1; ofs < 256; ofs <<= 1) {
        int v = (t >= ofs) ? sm[t - ofs] : 0;
        __syncthreads();
        sm[t] += v;
        __syncthreads();
    }
    const int boff = (blockIdx.x == 0) ? 0 : sm[blockIdx.x - 1];
    const int idx = blockIdx.x * 256 + t;
    if (idx < NN) {
        const int v = rowptr[idx] + boff;
        rowptr[idx] = v;
        cursor[idx] = v;
    }
    if (blockIdx.x == NB - 1 && t == 0) rowptr[NN] = sm[NB - 1];
}

// ---------------------------------------------------------------------------
// gather: z[n] = (1+eps[l])*f(src[n]) + sum_{c in adj[n]} f(src[c])
// 16 threads/node x 16B loads; 16 nodes per 256-thread block.
// ---------------------------------------------------------------------------
template <bool BN>
__global__ __launch_bounds__(256) void gather_kernel(
    const unsigned short* __restrict__ src, const int* __restrict__ rowptr,
    const int* __restrict__ adj, const float* __restrict__ stats,
    const float* __restrict__ gamma, const float* __restrict__ beta,
    const float* __restrict__ eps, int l, unsigned short* __restrict__ z)
{
    const int node = blockIdx.x * 16 + (threadIdx.x >> 4);
    const int c0 = (threadIdx.x & 15) * 8;
    if (node >= NN) return;
    float sc[8], sh[8];
    if (BN) {
#pragma unroll
        for (int j = 0; j < 8; j++) bn_ss(stats, gamma, beta, c0 + j, sc[j], sh[j]);
    }
    const float e = 1.0f + eps[l];
    float acc[8];
    {
        mu32x4 v = *(const mu32x4*)(src + (size_t)node * HD + c0);
        const unsigned short* u = (const unsigned short*)&v;
#pragma unroll
        for (int j = 0; j < 8; j++) {
            float f = bf2f(u[j]);
            if (BN) f = fmaxf(f * sc[j] + sh[j], 0.f);
            acc[j] = e * f;
        }
    }
    const int s = rowptr[node], t = rowptr[node + 1];
    int i = s;
    for (; i + 4 <= t; i += 4) {
        const int n0 = adj[i], n1 = adj[i + 1], n2 = adj[i + 2], n3 = adj[i + 3];
        mu32x4 v0 = *(const mu32x4*)(src + (size_t)n0 * HD + c0);
        mu32x4 v1 = *(const mu32x4*)(src + (size_t)n1 * HD + c0);
        mu32x4 v2 = *(const mu32x4*)(src + (size_t)n2 * HD + c0);
        mu32x4 v3 = *(const mu32x4*)(src + (size_t)n3 * HD + c0);
        const unsigned short* u0 = (const unsigned short*)&v0;
        const unsigned short* u1 = (const unsigned short*)&v1;
        const unsigned short* u2 = (const unsigned short*)&v2;
        const unsigned short* u3 = (const unsigned short*)&v3;
#pragma unroll
        for (int j = 0; j < 8; j++) {
            float f0 = bf2f(u0[j]), f1 = bf2f(u1[j]);
            float f2 = bf2f(u2[j]), f3 = bf2f(u3[j]);
            if (BN) {
                f0 = fmaxf(f0 * sc[j] + sh[j], 0.f);
                f1 = fmaxf(f1 * sc[j] + sh[j], 0.f);
                f2 = fmaxf(f2 * sc[j] + sh[j], 0.f);
                f3 = fmaxf(f3 * sc[j] + sh[j], 0.f);
            }
            acc[j] += (f0 + f1) + (f2 + f3);
        }
    }
    for (; i < t; i++) {
        mu32x4 v = *(const mu32x4*)(src + (size_t)adj[i] * HD + c0);
        const unsigned short* u = (const unsigned short*)&v;
#pragma unroll
        for (int j = 0; j < 8; j++) {
            float f = bf2f(u[j]);
            if (BN) f = fmaxf(f * sc[j] + sh[j], 0.f);
            acc[j] += f;
        }
    }
    mu16x4 o0, o1;
#pragma unroll
    for (int j = 0; j < 4; j++) o0[j] = f2bf(acc[j]);
#pragma unroll
    for (int j = 0; j < 4; j++) o1[j] = f2bf(acc[4 + j]);
    *(mu16x4*)(z + (size_t)node * HD + c0) = o0;
    *(mu16x4*)(z + (size_t)node * HD + c0 + 4) = o1;
}

// ---------------------------------------------------------------------------
// pooled[g] = sum over graph rows of BN+ReLU(y); then out[g] = pooled @ pw + pb
// ---------------------------------------------------------------------------
__global__ __launch_bounds__(256) void poolfinal_kernel(
    const unsigned short* __restrict__ y, const int* __restrict__ start,
    const float* __restrict__ stats, const float* __restrict__ gamma,
    const float* __restrict__ beta, const float* __restrict__ pw,
    const float* __restrict__ pb, float* __restrict__ out)
{
    __shared__ float red[16][128];
    __shared__ float pl[128];
    const int g = blockIdx.x;
    const int rg = threadIdx.x >> 4;
    const int c0 = (threadIdx.x & 15) * 8;
    float sc[8], sh[8];
#pragma unroll
    for (int j = 0; j < 8; j++) bn_ss(stats, gamma, beta, c0 + j, sc[j], sh[j]);
    int s = start[g], e = start[g + 1];
    if (s < 0) s = 0;
    if (e > NN) e = NN;
    float acc[8];
#pragma unroll
    for (int j = 0; j < 8; j++) acc[j] = 0.f;
    for (int n = s + rg; n < e; n += 16) {
        mu32x4 v = *(const mu32x4*)(y + (size_t)n * HD + c0);
        const unsigned short* u = (const unsigned short*)&v;
#pragma unroll
        for (int j = 0; j < 8; j++)
            acc[j] += fmaxf(bf2f(u[j]) * sc[j] + sh[j], 0.f);
    }
#pragma unroll
    for (int j = 0; j < 8; j++) red[rg][c0 + j] = acc[j];
    __syncthreads();
    if (threadIdx.x < 128) {
        float a = 0.f;
#pragma unroll
        for (int k = 0; k < 16; k++) a += red[k][threadIdx.x];
        pl[threadIdx.x] = a;
    }
    __syncthreads();
    const int o = threadIdx.x;
    float facc = pb[o];
#pragma unroll 4
    for (int k = 0; k < 128; k++) facc += pl[k] * pw[k * 256 + o];
    out[(size_t)g * 256 + o] = facc;
}

// ---------------------------------------------------------------------------
extern "C" void kernel_launch(void* const* d_in, const int* in_sizes, int n_in,
                              void* d_out, int out_size, void* d_ws, size_t ws_size,
                              hipStream_t stream)
{
    const float* x      = (const float*)d_in[0];
    const int*   edge   = (const int*)d_in[1];
    const int*   batch  = (const int*)d_in[2];
    const float* emb_W  = (const float*)d_in[4];
    const float* emb_b  = (const float*)d_in[5];
    const float* W1     = (const float*)d_in[6];
    const float* b1     = (const float*)d_in[7];
    const float* g1     = (const float*)d_in[8];
    const float* be1    = (const float*)d_in[9];
    const float* W2     = (const float*)d_in[10];
    const float* b2     = (const float*)d_in[11];
    const float* g2     = (const float*)d_in[12];
    const float* be2    = (const float*)d_in[13];
    const float* eps    = (const float*)d_in[14];
    const float* proj_W = (const float*)d_in[15];
    const float* proj_b = (const float*)d_in[16];
    float* out = (float*)d_out;

    char* ws = (char*)d_ws;
    size_t off = 0;
    auto take = [&](size_t bytes) -> char* {
        char* p = ws + off;
        off += (bytes + 255) & ~(size_t)255;
        return p;
    };
    float*          stats  = (float*)take(6 * SREG * 4);   // ~203 KB
    int*            scnt   = (int*)take(8 * 4);
    int*            start  = (int*)take((NG + 1) * 4);
    int*            deg    = (int*)take(NN * 4);
    int*            rowptr = (int*)take((NN + 1) * 4);
    int*            cursor = (int*)take(NN * 4);
    int*            bsum   = (int*)take(256 * 4);
    unsigned short* wt     = (unsigned short*)take((size_t)(8192 + 6 * 16384) * 2);
    int*            adj    = (int*)take((size_t)NE * 4);
    unsigned short* zbuf   = (unsigned short*)take((size_t)NN * HD * 2);
    unsigned short* y1buf  = (unsigned short*)take((size_t)NN * HD * 2);
    unsigned short* y2buf  = (unsigned short*)take((size_t)NN * HD * 2);

    const int gemm_grid = (NN + 63) / 64;  // 782
    auto st = [&](int r) { return stats + (size_t)r * SREG; };

    prew_kernel<<<(8192 + 6 * 16384 + 255) / 256, 256, 0, stream>>>(
        emb_W, W1, W2, wt, stats, scnt, deg);
    deg_kernel<<<FILLB, 256, 0, stream>>>(edge, deg);
    bscan_kernel<<<NB, 256, 0, stream>>>(deg, rowptr, bsum);
    scanfix_kernel<<<NB, 256, 0, stream>>>(bsum, rowptr, cursor);

    // packed: CSR fill (586 blocks) || embed GEMM (782 blocks)
    gemm_kernel<AD, 0, false, 1><<<FILLB + gemm_grid, 256, 0, stream>>>(
        x, wt, emb_b, nullptr, nullptr, nullptr, y2buf, nullptr,
        nullptr, gemm_grid, NN, edge, cursor, adj);

    for (int l = 0; l < 3; l++) {
        if (l == 0)
            gather_kernel<false><<<(NN + 15) / 16, 256, 0, stream>>>(
                y2buf, rowptr, adj, nullptr, nullptr, nullptr, eps, l, zbuf);
        else
            gather_kernel<true><<<(NN + 15) / 16, 256, 0, stream>>>(
                y2buf, rowptr, adj, st(2 * l - 1),
                g2 + (l - 1) * HD, be2 + (l - 1) * HD, eps, l, zbuf);
        gemm_kernel<HD, 1, true, 0><<<gemm_grid, 256, 0, stream>>>(
            zbuf, wt + 8192 + (size_t)l * 16384, b1 + l * HD,
            nullptr, nullptr, nullptr, y1buf, st(2 * l),
            scnt + 2 * l, gemm_grid, NN, nullptr, nullptr, nullptr);
        if (l < 2)
            gemm_kernel<HD, 2, true, 0><<<gemm_grid, 256, 0, stream>>>(
                y1buf, wt + 8192 + (size_t)(3 + l) * 16384, b2 + l * HD,
                st(2 * l), g1 + l * HD, be1 + l * HD, y2buf, st(2 * l + 1),
                scnt + 2 * l + 1, gemm_grid, NN, nullptr, nullptr, nullptr);
        else
            // packed: graph starts (196 blocks) || last GEMM2 (782 blocks)
            gemm_kernel<HD, 2, true, 2><<<NB + gemm_grid, 256, 0, stream>>>(
                y1buf, wt + 8192 + (size_t)(3 + l) * 16384, b2 + l * HD,
                st(2 * l), g1 + l * HD, be1 + l * HD, y2buf, st(2 * l + 1),
                scnt + 2 * l + 1, gemm_grid, NN, batch, start, nullptr);
    }

    poolfinal_kernel<<<NG, 256, 0, stream>>>(
        y2buf, start, st(5), g2 + 2 * HD, be2 + 2 * HD, proj_W, proj_b, out);
}

// Round 11
// 495.956 us; speedup vs baseline: 1.1615x; 1.1615x over previous
//
#include <hip/hip_runtime.h>
#include <stdint.h>

#define NN 50000   // nodes
#define NE 600000  // edges
#define NG 1000    // graphs
#define AD 64      // input feat
#define HD 128     // hidden
#define OD 256     // output
#define BN_EPS_F 1e-5f
#define INV_N (1.0f / 50000.0f)
#define NB 196     // scan blocks = ceil(NN/256)
#define FILLB 586  // fill tail blocks (4 edges/thread)

typedef __attribute__((ext_vector_type(8))) short  mbf16x8;
typedef __attribute__((ext_vector_type(4))) float  mf32x4;
typedef __attribute__((ext_vector_type(4))) unsigned short mu16x4;
typedef __attribute__((ext_vector_type(4))) unsigned int   mu32x4;

__device__ __forceinline__ float bf2f(unsigned short u) {
    union { unsigned int i; float f; } v; v.i = ((unsigned int)u) << 16; return v.f;
}
__device__ __forceinline__ unsigned short f2bf(float f) {
    union { float f; unsigned int i; } v; v.f = f;
    unsigned int r = v.i + 0x7fffu + ((v.i >> 16) & 1u);  // RNE
    return (unsigned short)(r >> 16);
}
// BN (scale, shift) for column c from raw sums
__device__ __forceinline__ void bn_ss(
    const float* __restrict__ stats, const float* __restrict__ gamma,
    const float* __restrict__ beta, int c, float& sc, float& sh)
{
    const float mean = stats[c] * INV_N;
    const float var = fmaxf(stats[128 + c] * INV_N - mean * mean, 0.f);
    const float inv = rsqrtf(var + BN_EPS_F);
    sc = gamma[c] * inv;
    sh = beta[c] - mean * sc;
}

// ---------------------------------------------------------------------------
// Weight pre-convert + transpose: wt[n][k] bf16 from W[k][n] fp32.
// Also zeroes stats (1536 floats) and deg (NN).
// ---------------------------------------------------------------------------
__global__ __launch_bounds__(256) void prew_kernel(
    const float* __restrict__ emb_W, const float* __restrict__ W1,
    const float* __restrict__ W2, unsigned short* __restrict__ wt,
    float* __restrict__ stats, int* __restrict__ deg)
{
    const int t = blockIdx.x * 256 + threadIdx.x;
    if (t < 1536) stats[t] = 0.f;
    if (t < NN) deg[t] = 0;
    if (t < 8192) {                    // emb: n=t>>6, k=t&63
        wt[t] = f2bf(emb_W[(t & 63) * 128 + (t >> 6)]);
    } else {
        const int t2 = t - 8192;
        if (t2 >= 6 * 16384) return;
        const int which = t2 >> 14, o = t2 & 16383;
        const int n = o >> 7, k = o & 127;
        const float* src = (which < 3) ? (W1 + (size_t)which * 16384)
                                       : (W2 + (size_t)(which - 3) * 16384);
        wt[t] = f2bf(src[k * 128 + n]);
    }
}

// ---------------------------------------------------------------------------
// GEMM: out_bf16[N,128] = A[N,K] @ Wt^T + bias
// B-fragments are read DIRECTLY from global (wt is L1/L2-resident, 32 KB)
// -> no ws LDS tile -> LDS ~19.5 KB -> much higher occupancy for staging.
// AMODE: 0 = A fp32, 1 = A bf16 plain, 2 = A bf16 with BN(stats_in)+ReLU
// SOUT:  per-column sum/sumsq via LDS reduce + 256 global atomics (compact)
// TAIL:  1 = CSR fill tail blocks, 2 = graph-starts tail blocks
// ---------------------------------------------------------------------------
template <int K, int AMODE, bool SOUT, int TAIL>
__global__ __launch_bounds__(256) void gemm_kernel(
    const void* __restrict__ in, const unsigned short* __restrict__ Wt,
    const float* __restrict__ bias, const float* __restrict__ stats_in,
    const float* __restrict__ gamma, const float* __restrict__ beta,
    unsigned short* __restrict__ out, float* __restrict__ stats_out, int n_rows,
    const int* __restrict__ t_a, int* __restrict__ t_b, int* __restrict__ t_c)
{
    constexpr int TAILB = (TAIL == 1) ? FILLB : (TAIL == 2) ? NB : 0;
    if (TAIL != 0 && (int)blockIdx.x < TAILB) {
        const int t = blockIdx.x * 256 + threadIdx.x;
        if constexpr (TAIL == 1) {
            const int e0 = t * 4;
            if (e0 < NE) {   // NE % 4 == 0
                const int4 rv = *(const int4*)(t_a + e0);
                const int4 cv = *(const int4*)(t_a + NE + e0);
                if ((unsigned)rv.x < NN && (unsigned)cv.x < NN)
                    t_c[atomicAdd(&t_b[rv.x], 1)] = cv.x;
                if ((unsigned)rv.y < NN && (unsigned)cv.y < NN)
                    t_c[atomicAdd(&t_b[rv.y], 1)] = cv.y;
                if ((unsigned)rv.z < NN && (unsigned)cv.z < NN)
                    t_c[atomicAdd(&t_b[rv.z], 1)] = cv.z;
                if ((unsigned)rv.w < NN && (unsigned)cv.w < NN)
                    t_c[atomicAdd(&t_b[rv.w], 1)] = cv.w;
            }
        } else {  // TAIL == 2: graph starts
            if (t < NN) {
                int b = t_a[t];
                int pb = (t == 0) ? -1 : t_a[t - 1];
                if (b > NG - 1) b = NG - 1;
                if (pb > NG - 1) pb = NG - 1;
                for (int g = pb + 1; g <= b; g++) t_b[g] = t;
                if (t == NN - 1)
                    for (int g = b + 1; g <= NG; g++) t_b[g] = NN;
            }
        }
        return;
    }
    const int bid = blockIdx.x - TAILB;

    constexpr int SA = K + 8;
    __shared__ unsigned short zs[64 * SA];
    __shared__ float ssl[128], ssh[128];
    __shared__ float lsum[128], lsq[128];

    const int tid = threadIdx.x;
    const int wave = tid >> 6, lane = tid & 63;
    const int row0 = bid * 64;

    if (SOUT && tid < 128) { lsum[tid] = 0.f; lsq[tid] = 0.f; }
    if (AMODE == 2) {
        if (tid < 128) {
            float sc, sh; bn_ss(stats_in, gamma, beta, tid, sc, sh);
            ssl[tid] = sc; ssh[tid] = sh;
        }
        __syncthreads();
    }

    // ---- stage A tile -> LDS ----
    if constexpr (AMODE == 0) {
        const float* src = (const float*)in;
        constexpr int LPR = K / 4;
        for (int i = tid; i < 64 * LPR; i += 256) {
            const int r = i / LPR, c4 = (i % LPR) * 4;
            mf32x4 v = {0.f, 0.f, 0.f, 0.f};
            if (row0 + r < n_rows)
                v = *(const mf32x4*)(src + (size_t)(row0 + r) * K + c4);
            mu16x4 o;
            o[0] = f2bf(v[0]); o[1] = f2bf(v[1]); o[2] = f2bf(v[2]); o[3] = f2bf(v[3]);
            *(mu16x4*)(&zs[r * SA + c4]) = o;
        }
    } else {
        const unsigned short* src = (const unsigned short*)in;
        constexpr int LPR = K / 8;
        float sc[8], sh[8];
        if constexpr (AMODE == 2) {
            const int c8 = (tid % LPR) * 8;   // fixed per thread (256 % LPR == 0)
#pragma unroll
            for (int j = 0; j < 8; j++) { sc[j] = ssl[c8 + j]; sh[j] = ssh[c8 + j]; }
        }
        for (int i = tid; i < 64 * LPR; i += 256) {
            const int r = i / LPR, c8 = (i % LPR) * 8;
            mu32x4 v = {0, 0, 0, 0};
            if (row0 + r < n_rows)
                v = *(const mu32x4*)(src + (size_t)(row0 + r) * K + c8);
            if constexpr (AMODE == 2) {
                const unsigned short* u = (const unsigned short*)&v;
                mu16x4 oa, ob;
#pragma unroll
                for (int j = 0; j < 4; j++)
                    oa[j] = f2bf(fmaxf(bf2f(u[j]) * sc[j] + sh[j], 0.f));
#pragma unroll
                for (int j = 0; j < 4; j++)
                    ob[j] = f2bf(fmaxf(bf2f(u[4 + j]) * sc[4 + j] + sh[4 + j], 0.f));
                *(mu16x4*)(&zs[r * SA + c8]) = oa;
                *(mu16x4*)(&zs[r * SA + c8 + 4]) = ob;
            } else {
                *(mu32x4*)(&zs[r * SA + c8]) = v;
            }
        }
    }
    __syncthreads();

    // ---- MFMA: B-frags direct from global (L1-resident) ----
    mf32x4 acc[8];
#pragma unroll
    for (int t = 0; t < 8; t++) acc[t] = {0.f, 0.f, 0.f, 0.f};
    const int m = wave * 16 + (lane & 15);
    const int kq = (lane >> 4) * 8;
    const unsigned short* wn = Wt + (lane & 15) * K;  // + t*16*K + k0
#pragma unroll 1
    for (int kk = 0; kk < K / 32; kk++) {
        const int k0 = kk * 32 + kq;
        mbf16x8 a = *(const mbf16x8*)(&zs[m * SA + k0]);
        mbf16x8 b0 = *(const mbf16x8*)(wn + 0 * 16 * K + k0);
        mbf16x8 b1 = *(const mbf16x8*)(wn + 1 * 16 * K + k0);
        mbf16x8 b2 = *(const mbf16x8*)(wn + 2 * 16 * K + k0);
        mbf16x8 b3 = *(const mbf16x8*)(wn + 3 * 16 * K + k0);
        mbf16x8 b4 = *(const mbf16x8*)(wn + 4 * 16 * K + k0);
        mbf16x8 b5 = *(const mbf16x8*)(wn + 5 * 16 * K + k0);
        mbf16x8 b6 = *(const mbf16x8*)(wn + 6 * 16 * K + k0);
        mbf16x8 b7 = *(const mbf16x8*)(wn + 7 * 16 * K + k0);
        acc[0] = __builtin_amdgcn_mfma_f32_16x16x32_bf16(a, b0, acc[0], 0, 0, 0);
        acc[1] = __builtin_amdgcn_mfma_f32_16x16x32_bf16(a, b1, acc[1], 0, 0, 0);
        acc[2] = __builtin_amdgcn_mfma_f32_16x16x32_bf16(a, b2, acc[2], 0, 0, 0);
        acc[3] = __builtin_amdgcn_mfma_f32_16x16x32_bf16(a, b3, acc[3], 0, 0, 0);
        acc[4] = __builtin_amdgcn_mfma_f32_16x16x32_bf16(a, b4, acc[4], 0, 0, 0);
        acc[5] = __builtin_amdgcn_mfma_f32_16x16x32_bf16(a, b5, acc[5], 0, 0, 0);
        acc[6] = __builtin_amdgcn_mfma_f32_16x16x32_bf16(a, b6, acc[6], 0, 0, 0);
        acc[7] = __builtin_amdgcn_mfma_f32_16x16x32_bf16(a, b7, acc[7], 0, 0, 0);
    }

    // ---- epilogue: +bias, store bf16; fused column stats (compact atomics) ----
    const int rbase = wave * 16 + ((lane >> 4) << 2);
#pragma unroll
    for (int t = 0; t < 8; t++) {
        const int c = t * 16 + (lane & 15);
        const float bv = bias[c];
        float s = 0.f, q = 0.f;
#pragma unroll
        for (int r = 0; r < 4; r++) {
            const int grow = row0 + rbase + r;
            const float y = acc[t][r] + bv;
            if (grow < n_rows) {
                out[(size_t)grow * 128 + c] = f2bf(y);
                if (SOUT) { s += y; q += y * y; }
            }
        }
        if (SOUT) {
            s += __shfl_xor(s, 16); s += __shfl_xor(s, 32);
            q += __shfl_xor(q, 16); q += __shfl_xor(q, 32);
            if ((lane >> 4) == 0) {
                atomicAdd(&lsum[c], s);
                atomicAdd(&lsq[c], q);
            }
        }
    }
    if (SOUT) {
        __syncthreads();
        if (tid < 128) {
            atomicAdd(&stats_out[tid], lsum[tid]);
            atomicAdd(&stats_out[128 + tid], lsq[tid]);
        }
    }
}

// ---------------------------------------------------------------------------
// CSR build: histogram (4 edges/thread) -> bscan -> scanfix
// ---------------------------------------------------------------------------
__global__ __launch_bounds__(256) void deg_kernel(
    const int* __restrict__ ei, int* __restrict__ deg)
{
    const int e0 = (blockIdx.x * 256 + threadIdx.x) * 4;
    if (e0 >= NE) return;   // NE % 4 == 0
    const int4 rv = *(const int4*)(ei + e0);
    if ((unsigned)rv.x < NN) atomicAdd(&deg[rv.x], 1);
    if ((unsigned)rv.y < NN) atomicAdd(&deg[rv.y], 1);
    if ((unsigned)rv.z < NN) atomicAdd(&deg[rv.z], 1);
    if ((unsigned)rv.w < NN) atomicAdd(&deg[rv.w], 1);
}

__global__ __launch_bounds__(256) void bscan_kernel(
    const int* __restrict__ deg, int* __restrict__ rowptr, int* __restrict__ bsum)
{
    __shared__ int sm[256];
    const int t = threadIdx.x, idx = blockIdx.x * 256 + t;
    const int d = (idx < NN) ? deg[idx] : 0;
    sm[t] = d; __syncthreads();
    for (int ofs = 1; ofs < 256; ofs <<= 1) {
        int v = (t >= ofs) ? sm[t - ofs] : 0;
        __syncthreads();
        sm[t] += v;
        __syncthreads();
    }
    if (idx < NN) rowptr[idx] = sm[t] - d;  // exclusive, block-local
    if (t == 255) bsum[blockIdx.x] = sm[255];
}

// each block re-scans bsum itself, adds its offset, fills cursor
__global__ __launch_bounds__(256) void scanfix_kernel(
    const int* __restrict__ bsum, int* __restrict__ rowptr, int* __restrict__ cursor)
{
    __shared__ int sm[256];
    const int t = threadIdx.x;
    const int d = (t < NB) ? bsum[t] : 0;
    sm[t] = d; __syncthreads();
    for (int ofs = 1; ofs < 256; ofs <<= 1) {
        int v = (t >= ofs) ? sm[t - ofs] : 0;
        __syncthreads();
        sm[t] += v;
        __syncthreads();
    }
    const int boff = (blockIdx.x == 0) ? 0 : sm[blockIdx.x - 1];
    const int idx = blockIdx.x * 256 + t;
    if (idx < NN) {
        const int v = rowptr[idx] + boff;
        rowptr[idx] = v;
        cursor[idx] = v;
    }
    if (blockIdx.x == NB - 1 && t == 0) rowptr[NN] = sm[NB - 1];
}

// ---------------------------------------------------------------------------
// gather: z[n] = (1+eps[l])*f(src[n]) + sum_{c in adj[n]} f(src[c])
// 16 threads/node x 16B loads; 16 nodes per 256-thread block.
// ---------------------------------------------------------------------------
template <bool BN>
__global__ __launch_bounds__(256) void gather_kernel(
    const unsigned short* __restrict__ src, const int* __restrict__ rowptr,
    const int* __restrict__ adj, const float* __restrict__ stats,
    const float* __restrict__ gamma, const float* __restrict__ beta,
    const float* __restrict__ eps, int l, unsigned short* __restrict__ z)
{
    const int node = blockIdx.x * 16 + (threadIdx.x >> 4);
    const int c0 = (threadIdx.x & 15) * 8;
    if (node >= NN) return;
    float sc[8], sh[8];
    if (BN) {
#pragma unroll
        for (int j = 0; j < 8; j++) bn_ss(stats, gamma, beta, c0 + j, sc[j], sh[j]);
    }
    const float e = 1.0f + eps[l];
    float acc[8];
    {
        mu32x4 v = *(const mu32x4*)(src + (size_t)node * HD + c0);
        const unsigned short* u = (const unsigned short*)&v;
#pragma unroll
        for (int j = 0; j < 8; j++) {
            float f = bf2f(u[j]);
            if (BN) f = fmaxf(f * sc[j] + sh[j], 0.f);
            acc[j] = e * f;
        }
    }
    const int s = rowptr[node], t = rowptr[node + 1];
    int i = s;
    for (; i + 4 <= t; i += 4) {
        const int n0 = adj[i], n1 = adj[i + 1], n2 = adj[i + 2], n3 = adj[i + 3];
        mu32x4 v0 = *(const mu32x4*)(src + (size_t)n0 * HD + c0);
        mu32x4 v1 = *(const mu32x4*)(src + (size_t)n1 * HD + c0);
        mu32x4 v2 = *(const mu32x4*)(src + (size_t)n2 * HD + c0);
        mu32x4 v3 = *(const mu32x4*)(src + (size_t)n3 * HD + c0);
        const unsigned short* u0 = (const unsigned short*)&v0;
        const unsigned short* u1 = (const unsigned short*)&v1;
        const unsigned short* u2 = (const unsigned short*)&v2;
        const unsigned short* u3 = (const unsigned short*)&v3;
#pragma unroll
        for (int j = 0; j < 8; j++) {
            float f0 = bf2f(u0[j]), f1 = bf2f(u1[j]);
            float f2 = bf2f(u2[j]), f3 = bf2f(u3[j]);
            if (BN) {
                f0 = fmaxf(f0 * sc[j] + sh[j], 0.f);
                f1 = fmaxf(f1 * sc[j] + sh[j], 0.f);
                f2 = fmaxf(f2 * sc[j] + sh[j], 0.f);
                f3 = fmaxf(f3 * sc[j] + sh[j], 0.f);
            }
            acc[j] += (f0 + f1) + (f2 + f3);
        }
    }
    for (; i < t; i++) {
        mu32x4 v = *(const mu32x4*)(src + (size_t)adj[i] * HD + c0);
        const unsigned short* u = (const unsigned short*)&v;
#pragma unroll
        for (int j = 0; j < 8; j++) {
            float f = bf2f(u[j]);
            if (BN) f = fmaxf(f * sc[j] + sh[j], 0.f);
            acc[j] += f;
        }
    }
    mu16x4 o0, o1;
#pragma unroll
    for (int j = 0; j < 4; j++) o0[j] = f2bf(acc[j]);
#pragma unroll
    for (int j = 0; j < 4; j++) o1[j] = f2bf(acc[4 + j]);
    *(mu16x4*)(z + (size_t)node * HD + c0) = o0;
    *(mu16x4*)(z + (size_t)node * HD + c0 + 4) = o1;
}

// ---------------------------------------------------------------------------
// pooled[g] = sum over graph rows of BN+ReLU(y); then out[g] = pooled @ pw + pb
// ---------------------------------------------------------------------------
__global__ __launch_bounds__(256) void poolfinal_kernel(
    const unsigned short* __restrict__ y, const int* __restrict__ start,
    const float* __restrict__ stats, const float* __restrict__ gamma,
    const float* __restrict__ beta, const float* __restrict__ pw,
    const float* __restrict__ pb, float* __restrict__ out)
{
    __shared__ float red[16][128];
    __shared__ float pl[128];
    const int g = blockIdx.x;
    const int rg = threadIdx.x >> 4;
    const int c0 = (threadIdx.x & 15) * 8;
    float sc[8], sh[8];
#pragma unroll
    for (int j = 0; j < 8; j++) bn_ss(stats, gamma, beta, c0 + j, sc[j], sh[j]);
    int s = start[g], e = start[g + 1];
    if (s < 0) s = 0;
    if (e > NN) e = NN;
    float acc[8];
#pragma unroll
    for (int j = 0; j < 8; j++) acc[j] = 0.f;
    for (int n = s + rg; n < e; n += 16) {
        mu32x4 v = *(const mu32x4*)(y + (size_t)n * HD + c0);
        const unsigned short* u = (const unsigned short*)&v;
#pragma unroll
        for (int j = 0; j < 8; j++)
            acc[j] += fmaxf(bf2f(u[j]) * sc[j] + sh[j], 0.f);
    }
#pragma unroll
    for (int j = 0; j < 8; j++) red[rg][c0 + j] = acc[j];
    __syncthreads();
    if (threadIdx.x < 128) {
        float a = 0.f;
#pragma unroll
        for (int k = 0; k < 16; k++) a += red[k][threadIdx.x];
        pl[threadIdx.x] = a;
    }
    __syncthreads();
    const int o = threadIdx.x;
    float facc = pb[o];
#pragma unroll 4
    for (int k = 0; k < 128; k++) facc += pl[k] * pw[k * 256 + o];
    out[(size_t)g * 256 + o] = facc;
}

// ---------------------------------------------------------------------------
extern "C" void kernel_launch(void* const* d_in, const int* in_sizes, int n_in,
                              void* d_out, int out_size, void* d_ws, size_t ws_size,
                              hipStream_t stream)
{
    const float* x      = (const float*)d_in[0];
    const int*   edge   = (const int*)d_in[1];
    const int*   batch  = (const int*)d_in[2];
    const float* emb_W  = (const float*)d_in[4];
    const float* emb_b  = (const float*)d_in[5];
    const float* W1     = (const float*)d_in[6];
    const float* b1     = (const float*)d_in[7];
    const float* g1     = (const float*)d_in[8];
    const float* be1    = (const float*)d_in[9];
    const float* W2     = (const float*)d_in[10];
    const float* b2     = (const float*)d_in[11];
    const float* g2     = (const float*)d_in[12];
    const float* be2    = (const float*)d_in[13];
    const float* eps    = (const float*)d_in[14];
    const float* proj_W = (const float*)d_in[15];
    const float* proj_b = (const float*)d_in[16];
    float* out = (float*)d_out;

    char* ws = (char*)d_ws;
    size_t off = 0;
    auto take = [&](size_t bytes) -> char* {
        char* p = ws + off;
        off += (bytes + 255) & ~(size_t)255;
        return p;
    };
    float*          stats  = (float*)take(6 * 2 * HD * 4);
    int*            start  = (int*)take((NG + 1) * 4);
    int*            deg    = (int*)take(NN * 4);
    int*            rowptr = (int*)take((NN + 1) * 4);
    int*            cursor = (int*)take(NN * 4);
    int*            bsum   = (int*)take(256 * 4);
    unsigned short* wt     = (unsigned short*)take((size_t)(8192 + 6 * 16384) * 2);
    int*            adj    = (int*)take((size_t)NE * 4);
    unsigned short* zbuf   = (unsigned short*)take((size_t)NN * HD * 2);
    unsigned short* y1buf  = (unsigned short*)take((size_t)NN * HD * 2);
    unsigned short* y2buf  = (unsigned short*)take((size_t)NN * HD * 2);

    const int gemm_grid = (NN + 63) / 64;  // 782
    auto st = [&](int r) { return stats + (size_t)r * 256; };

    prew_kernel<<<(8192 + 6 * 16384 + 255) / 256, 256, 0, stream>>>(
        emb_W, W1, W2, wt, stats, deg);
    deg_kernel<<<FILLB, 256, 0, stream>>>(edge, deg);
    bscan_kernel<<<NB, 256, 0, stream>>>(deg, rowptr, bsum);
    scanfix_kernel<<<NB, 256, 0, stream>>>(bsum, rowptr, cursor);

    // packed: CSR fill (586 blocks) || embed GEMM (782 blocks)
    gemm_kernel<AD, 0, false, 1><<<FILLB + gemm_grid, 256, 0, stream>>>(
        x, wt, emb_b, nullptr, nullptr, nullptr, y2buf, nullptr, NN,
        edge, cursor, adj);

    for (int l = 0; l < 3; l++) {
        if (l == 0)
            gather_kernel<false><<<(NN + 15) / 16, 256, 0, stream>>>(
                y2buf, rowptr, adj, nullptr, nullptr, nullptr, eps, l, zbuf);
        else
            gather_kernel<true><<<(NN + 15) / 16, 256, 0, stream>>>(
                y2buf, rowptr, adj, st(2 * l - 1),
                g2 + (l - 1) * HD, be2 + (l - 1) * HD, eps, l, zbuf);
        gemm_kernel<HD, 1, true, 0><<<gemm_grid, 256, 0, stream>>>(
            zbuf, wt + 8192 + (size_t)l * 16384, b1 + l * HD,
            nullptr, nullptr, nullptr, y1buf, st(2 * l), NN,
            nullptr, nullptr, nullptr);
        if (l < 2)
            gemm_kernel<HD, 2, true, 0><<<gemm_grid, 256, 0, stream>>>(
                y1buf, wt + 8192 + (size_t)(3 + l) * 16384, b2 + l * HD,
                st(2 * l), g1 + l * HD, be1 + l * HD, y2buf, st(2 * l + 1), NN,
                nullptr, nullptr, nullptr);
        else
            // packed: graph starts (196 blocks) || last GEMM2 (782 blocks)
            gemm_kernel<HD, 2, true, 2><<<NB + gemm_grid, 256, 0, stream>>>(
                y1buf, wt + 8192 + (size_t)(3 + l) * 16384, b2 + l * HD,
                st(2 * l), g1 + l * HD, be1 + l * HD, y2buf, st(2 * l + 1), NN,
                batch, start, nullptr);
    }

    poolfinal_kernel<<<NG, 256, 0, stream>>>(
        y2buf, start, st(5), g2 + 2 * HD, be2 + 2 * HD, proj_W, proj_b, out);
}

// Round 12
// 425.409 us; speedup vs baseline: 1.3541x; 1.1658x over previous
//
#include <hip/hip_runtime.h>
#include <stdint.h>

#define NN 50000   // nodes
#define NE 600000  // edges
#define NG 1000    // graphs
#define AD 64      // input feat
#define HD 128     // hidden
#define OD 256     // output
#define BN_EPS_F 1e-5f
#define INV_N (1.0f / 50000.0f)
#define NB 196     // scan blocks = ceil(NN/256)
#define FILLB 586  // fill tail blocks (4 edges/thread)
#define NCOPY 32   // stats spread copies (256 floats each)
#define SREG (NCOPY * 256)  // floats per stat region

typedef __attribute__((ext_vector_type(8))) short  mbf16x8;
typedef __attribute__((ext_vector_type(4))) float  mf32x4;
typedef __attribute__((ext_vector_type(4))) unsigned short mu16x4;
typedef __attribute__((ext_vector_type(4))) unsigned int   mu32x4;

__device__ __forceinline__ float bf2f(unsigned short u) {
    union { unsigned int i; float f; } v; v.i = ((unsigned int)u) << 16; return v.f;
}
__device__ __forceinline__ unsigned short f2bf(float f) {
    union { float f; unsigned int i; } v; v.f = f;
    unsigned int r = v.i + 0x7fffu + ((v.i >> 16) & 1u);  // RNE
    return (unsigned short)(r >> 16);
}
// BN (scale, shift) for column c from folded raw sums (any address space)
__device__ __forceinline__ void bn_ss(
    const float* stats, const float* __restrict__ gamma,
    const float* __restrict__ beta, int c, float& sc, float& sh)
{
    const float mean = stats[c] * INV_N;
    const float var = fmaxf(stats[128 + c] * INV_N - mean * mean, 0.f);
    const float inv = rsqrtf(var + BN_EPS_F);
    sc = gamma[c] * inv;
    sh = beta[c] - mean * sc;
}
// fold 32 spread copies of stat index t (t < 256) from a region
__device__ __forceinline__ float fold_stat(const float* __restrict__ reg, int t)
{
    float a = 0.f;
#pragma unroll
    for (int c = 0; c < NCOPY; c++) a += reg[c * 256 + t];
    return a;
}

// ---------------------------------------------------------------------------
// Weight pre-convert + transpose: wt[n][k] bf16 from W[k][n] fp32.
// Also zeroes stats regions (6*SREG floats) and deg (NN).
// ---------------------------------------------------------------------------
__global__ __launch_bounds__(256) void prew_kernel(
    const float* __restrict__ emb_W, const float* __restrict__ W1,
    const float* __restrict__ W2, unsigned short* __restrict__ wt,
    float* __restrict__ stats, int* __restrict__ deg)
{
    const int t = blockIdx.x * 256 + threadIdx.x;
    if (t < 6 * SREG) stats[t] = 0.f;
    if (t < NN) deg[t] = 0;
    if (t < 8192) {                    // emb: n=t>>6, k=t&63
        wt[t] = f2bf(emb_W[(t & 63) * 128 + (t >> 6)]);
    } else {
        const int t2 = t - 8192;
        if (t2 >= 6 * 16384) return;
        const int which = t2 >> 14, o = t2 & 16383;
        const int n = o >> 7, k = o & 127;
        const float* src = (which < 3) ? (W1 + (size_t)which * 16384)
                                       : (W2 + (size_t)(which - 3) * 16384);
        wt[t] = f2bf(src[k * 128 + n]);
    }
}

// ---------------------------------------------------------------------------
// GEMM: out_bf16[N,128] = A[N,K] @ Wt^T + bias   (B direct from global)
// AMODE: 0 = A fp32, 1 = A bf16 plain, 2 = A bf16 with BN(stats_in)+ReLU
// SOUT:  per-column sum/sumsq -> spread copy (bid&31); NO fold, NO fence.
//        Consumers (later kernels) fold the 32 copies themselves.
// TAIL:  1 = CSR fill tail blocks, 2 = graph-starts tail blocks
// ---------------------------------------------------------------------------
template <int K, int AMODE, bool SOUT, int TAIL>
__global__ __launch_bounds__(256) void gemm_kernel(
    const void* __restrict__ in, const unsigned short* __restrict__ Wt,
    const float* __restrict__ bias, const float* __restrict__ stats_in,
    const float* __restrict__ gamma, const float* __restrict__ beta,
    unsigned short* __restrict__ out, float* __restrict__ stats_out, int n_rows,
    const int* __restrict__ t_a, int* __restrict__ t_b, int* __restrict__ t_c)
{
    constexpr int TAILB = (TAIL == 1) ? FILLB : (TAIL == 2) ? NB : 0;
    if (TAIL != 0 && (int)blockIdx.x < TAILB) {
        const int t = blockIdx.x * 256 + threadIdx.x;
        if constexpr (TAIL == 1) {
            const int e0 = t * 4;
            if (e0 < NE) {   // NE % 4 == 0
                const int4 rv = *(const int4*)(t_a + e0);
                const int4 cv = *(const int4*)(t_a + NE + e0);
                if ((unsigned)rv.x < NN && (unsigned)cv.x < NN)
                    t_c[atomicAdd(&t_b[rv.x], 1)] = cv.x;
                if ((unsigned)rv.y < NN && (unsigned)cv.y < NN)
                    t_c[atomicAdd(&t_b[rv.y], 1)] = cv.y;
                if ((unsigned)rv.z < NN && (unsigned)cv.z < NN)
                    t_c[atomicAdd(&t_b[rv.z], 1)] = cv.z;
                if ((unsigned)rv.w < NN && (unsigned)cv.w < NN)
                    t_c[atomicAdd(&t_b[rv.w], 1)] = cv.w;
            }
        } else {  // TAIL == 2: graph starts
            if (t < NN) {
                int b = t_a[t];
                int pb = (t == 0) ? -1 : t_a[t - 1];
                if (b > NG - 1) b = NG - 1;
                if (pb > NG - 1) pb = NG - 1;
                for (int g = pb + 1; g <= b; g++) t_b[g] = t;
                if (t == NN - 1)
                    for (int g = b + 1; g <= NG; g++) t_b[g] = NN;
            }
        }
        return;
    }
    const int bid = blockIdx.x - TAILB;

    constexpr int SA = K + 8;
    __shared__ unsigned short zs[64 * SA];
    __shared__ float ssl[128], ssh[128];
    __shared__ float lsum[128], lsq[128];
    __shared__ float sarr[256];

    const int tid = threadIdx.x;
    const int wave = tid >> 6, lane = tid & 63;
    const int row0 = bid * 64;

    if (SOUT && tid < 128) { lsum[tid] = 0.f; lsq[tid] = 0.f; }
    if (AMODE == 2) {
        // fold spread stats -> LDS, then BN scale/shift
        sarr[tid] = fold_stat(stats_in, tid);
        __syncthreads();
        if (tid < 128) {
            float sc, sh; bn_ss(sarr, gamma, beta, tid, sc, sh);
            ssl[tid] = sc; ssh[tid] = sh;
        }
        __syncthreads();
    }

    // ---- stage A tile -> LDS ----
    if constexpr (AMODE == 0) {
        const float* src = (const float*)in;
        constexpr int LPR = K / 4;
        for (int i = tid; i < 64 * LPR; i += 256) {
            const int r = i / LPR, c4 = (i % LPR) * 4;
            mf32x4 v = {0.f, 0.f, 0.f, 0.f};
            if (row0 + r < n_rows)
                v = *(const mf32x4*)(src + (size_t)(row0 + r) * K + c4);
            mu16x4 o;
            o[0] = f2bf(v[0]); o[1] = f2bf(v[1]); o[2] = f2bf(v[2]); o[3] = f2bf(v[3]);
            *(mu16x4*)(&zs[r * SA + c4]) = o;
        }
    } else {
        const unsigned short* src = (const unsigned short*)in;
        constexpr int LPR = K / 8;
        float sc[8], sh[8];
        if constexpr (AMODE == 2) {
            const int c8 = (tid % LPR) * 8;   // fixed per thread (256 % LPR == 0)
#pragma unroll
            for (int j = 0; j < 8; j++) { sc[j] = ssl[c8 + j]; sh[j] = ssh[c8 + j]; }
        }
        for (int i = tid; i < 64 * LPR; i += 256) {
            const int r = i / LPR, c8 = (i % LPR) * 8;
            mu32x4 v = {0, 0, 0, 0};
            if (row0 + r < n_rows)
                v = *(const mu32x4*)(src + (size_t)(row0 + r) * K + c8);
            if constexpr (AMODE == 2) {
                const unsigned short* u = (const unsigned short*)&v;
                mu16x4 oa, ob;
#pragma unroll
                for (int j = 0; j < 4; j++)
                    oa[j] = f2bf(fmaxf(bf2f(u[j]) * sc[j] + sh[j], 0.f));
#pragma unroll
                for (int j = 0; j < 4; j++)
                    ob[j] = f2bf(fmaxf(bf2f(u[4 + j]) * sc[4 + j] + sh[4 + j], 0.f));
                *(mu16x4*)(&zs[r * SA + c8]) = oa;
                *(mu16x4*)(&zs[r * SA + c8 + 4]) = ob;
            } else {
                *(mu32x4*)(&zs[r * SA + c8]) = v;
            }
        }
    }
    __syncthreads();

    // ---- MFMA: B-frags direct from global (L1-resident) ----
    mf32x4 acc[8];
#pragma unroll
    for (int t = 0; t < 8; t++) acc[t] = {0.f, 0.f, 0.f, 0.f};
    const int m = wave * 16 + (lane & 15);
    const int kq = (lane >> 4) * 8;
    const unsigned short* wn = Wt + (lane & 15) * K;  // + t*16*K + k0
#pragma unroll 1
    for (int kk = 0; kk < K / 32; kk++) {
        const int k0 = kk * 32 + kq;
        mbf16x8 a = *(const mbf16x8*)(&zs[m * SA + k0]);
        mbf16x8 b0 = *(const mbf16x8*)(wn + 0 * 16 * K + k0);
        mbf16x8 b1 = *(const mbf16x8*)(wn + 1 * 16 * K + k0);
        mbf16x8 b2 = *(const mbf16x8*)(wn + 2 * 16 * K + k0);
        mbf16x8 b3 = *(const mbf16x8*)(wn + 3 * 16 * K + k0);
        mbf16x8 b4 = *(const mbf16x8*)(wn + 4 * 16 * K + k0);
        mbf16x8 b5 = *(const mbf16x8*)(wn + 5 * 16 * K + k0);
        mbf16x8 b6 = *(const mbf16x8*)(wn + 6 * 16 * K + k0);
        mbf16x8 b7 = *(const mbf16x8*)(wn + 7 * 16 * K + k0);
        acc[0] = __builtin_amdgcn_mfma_f32_16x16x32_bf16(a, b0, acc[0], 0, 0, 0);
        acc[1] = __builtin_amdgcn_mfma_f32_16x16x32_bf16(a, b1, acc[1], 0, 0, 0);
        acc[2] = __builtin_amdgcn_mfma_f32_16x16x32_bf16(a, b2, acc[2], 0, 0, 0);
        acc[3] = __builtin_amdgcn_mfma_f32_16x16x32_bf16(a, b3, acc[3], 0, 0, 0);
        acc[4] = __builtin_amdgcn_mfma_f32_16x16x32_bf16(a, b4, acc[4], 0, 0, 0);
        acc[5] = __builtin_amdgcn_mfma_f32_16x16x32_bf16(a, b5, acc[5], 0, 0, 0);
        acc[6] = __builtin_amdgcn_mfma_f32_16x16x32_bf16(a, b6, acc[6], 0, 0, 0);
        acc[7] = __builtin_amdgcn_mfma_f32_16x16x32_bf16(a, b7, acc[7], 0, 0, 0);
    }

    // ---- epilogue: +bias, store bf16; stats -> spread copy (bid&31) ----
    const int rbase = wave * 16 + ((lane >> 4) << 2);
#pragma unroll
    for (int t = 0; t < 8; t++) {
        const int c = t * 16 + (lane & 15);
        const float bv = bias[c];
        float s = 0.f, q = 0.f;
#pragma unroll
        for (int r = 0; r < 4; r++) {
            const int grow = row0 + rbase + r;
            const float y = acc[t][r] + bv;
            if (grow < n_rows) {
                out[(size_t)grow * 128 + c] = f2bf(y);
                if (SOUT) { s += y; q += y * y; }
            }
        }
        if (SOUT) {
            s += __shfl_xor(s, 16); s += __shfl_xor(s, 32);
            q += __shfl_xor(q, 16); q += __shfl_xor(q, 32);
            if ((lane >> 4) == 0) {
                atomicAdd(&lsum[c], s);
                atomicAdd(&lsq[c], q);
            }
        }
    }
    if (SOUT) {
        __syncthreads();
        float* cb = stats_out + (bid & (NCOPY - 1)) * 256;
        if (tid < 128) {
            atomicAdd(&cb[tid], lsum[tid]);
            atomicAdd(&cb[128 + tid], lsq[tid]);
        }
    }
}

// ---------------------------------------------------------------------------
// CSR build: histogram (4 edges/thread) -> bscan -> scanfix
// ---------------------------------------------------------------------------
__global__ __launch_bounds__(256) void deg_kernel(
    const int* __restrict__ ei, int* __restrict__ deg)
{
    const int e0 = (blockIdx.x * 256 + threadIdx.x) * 4;
    if (e0 >= NE) return;   // NE % 4 == 0
    const int4 rv = *(const int4*)(ei + e0);
    if ((unsigned)rv.x < NN) atomicAdd(&deg[rv.x], 1);
    if ((unsigned)rv.y < NN) atomicAdd(&deg[rv.y], 1);
    if ((unsigned)rv.z < NN) atomicAdd(&deg[rv.z], 1);
    if ((unsigned)rv.w < NN) atomicAdd(&deg[rv.w], 1);
}

__global__ __launch_bounds__(256) void bscan_kernel(
    const int* __restrict__ deg, int* __restrict__ rowptr, int* __restrict__ bsum)
{
    __shared__ int sm[256];
    const int t = threadIdx.x, idx = blockIdx.x * 256 + t;
    const int d = (idx < NN) ? deg[idx] : 0;
    sm[t] = d; __syncthreads();
    for (int ofs = 1; ofs < 256; ofs <<= 1) {
        int v = (t >= ofs) ? sm[t - ofs] : 0;
        __syncthreads();
        sm[t] += v;
        __syncthreads();
    }
    if (idx < NN) rowptr[idx] = sm[t] - d;  // exclusive, block-local
    if (t == 255) bsum[blockIdx.x] = sm[255];
}

// each block re-scans bsum itself, adds its offset, fills cursor
__global__ __launch_bounds__(256) void scanfix_kernel(
    const int* __restrict__ bsum, int* __restrict__ rowptr, int* __restrict__ cursor)
{
    __shared__ int sm[256];
    const int t = threadIdx.x;
    const int d = (t < NB) ? bsum[t] : 0;
    sm[t] = d; __syncthreads();
    for (int ofs = 1; ofs < 256; ofs <<= 1) {
        int v = (t >= ofs) ? sm[t - ofs] : 0;
        __syncthreads();
        sm[t] += v;
        __syncthreads();
    }
    const int boff = (blockIdx.x == 0) ? 0 : sm[blockIdx.x - 1];
    const int idx = blockIdx.x * 256 + t;
    if (idx < NN) {
        const int v = rowptr[idx] + boff;
        rowptr[idx] = v;
        cursor[idx] = v;
    }
    if (blockIdx.x == NB - 1 && t == 0) rowptr[NN] = sm[NB - 1];
}

// ---------------------------------------------------------------------------
// gather: z[n] = (1+eps[l])*f(src[n]) + sum_{c in adj[n]} f(src[c])
// f = BN+ReLU (folded from spread stats) when BN, else identity.
// 16 threads/node x 16B loads; 16 nodes per 256-thread block.
// ---------------------------------------------------------------------------
template <bool BN>
__global__ __launch_bounds__(256) void gather_kernel(
    const unsigned short* __restrict__ src, const int* __restrict__ rowptr,
    const int* __restrict__ adj, const float* __restrict__ stats,
    const float* __restrict__ gamma, const float* __restrict__ beta,
    const float* __restrict__ eps, int l, unsigned short* __restrict__ z)
{
    __shared__ float sarr[256];
    if constexpr (BN) {
        sarr[threadIdx.x] = fold_stat(stats, threadIdx.x);
        __syncthreads();
    }
    const int node = blockIdx.x * 16 + (threadIdx.x >> 4);
    const int c0 = (threadIdx.x & 15) * 8;
    if (node >= NN) return;   // never taken: NN % 16 == 0
    float sc[8], sh[8];
    if (BN) {
#pragma unroll
        for (int j = 0; j < 8; j++) bn_ss(sarr, gamma, beta, c0 + j, sc[j], sh[j]);
    }
    const float e = 1.0f + eps[l];
    float acc[8];
    {
        mu32x4 v = *(const mu32x4*)(src + (size_t)node * HD + c0);
        const unsigned short* u = (const unsigned short*)&v;
#pragma unroll
        for (int j = 0; j < 8; j++) {
            float f = bf2f(u[j]);
            if (BN) f = fmaxf(f * sc[j] + sh[j], 0.f);
            acc[j] = e * f;
        }
    }
    const int s = rowptr[node], t = rowptr[node + 1];
    int i = s;
    for (; i + 4 <= t; i += 4) {
        const int n0 = adj[i], n1 = adj[i + 1], n2 = adj[i + 2], n3 = adj[i + 3];
        mu32x4 v0 = *(const mu32x4*)(src + (size_t)n0 * HD + c0);
        mu32x4 v1 = *(const mu32x4*)(src + (size_t)n1 * HD + c0);
        mu32x4 v2 = *(const mu32x4*)(src + (size_t)n2 * HD + c0);
        mu32x4 v3 = *(const mu32x4*)(src + (size_t)n3 * HD + c0);
        const unsigned short* u0 = (const unsigned short*)&v0;
        const unsigned short* u1 = (const unsigned short*)&v1;
        const unsigned short* u2 = (const unsigned short*)&v2;
        const unsigned short* u3 = (const unsigned short*)&v3;
#pragma unroll
        for (int j = 0; j < 8; j++) {
            float f0 = bf2f(u0[j]), f1 = bf2f(u1[j]);
            float f2 = bf2f(u2[j]), f3 = bf2f(u3[j]);
            if (BN) {
                f0 = fmaxf(f0 * sc[j] + sh[j], 0.f);
                f1 = fmaxf(f1 * sc[j] + sh[j], 0.f);
                f2 = fmaxf(f2 * sc[j] + sh[j], 0.f);
                f3 = fmaxf(f3 * sc[j] + sh[j], 0.f);
            }
            acc[j] += (f0 + f1) + (f2 + f3);
        }
    }
    for (; i < t; i++) {
        mu32x4 v = *(const mu32x4*)(src + (size_t)adj[i] * HD + c0);
        const unsigned short* u = (const unsigned short*)&v;
#pragma unroll
        for (int j = 0; j < 8; j++) {
            float f = bf2f(u[j]);
            if (BN) f = fmaxf(f * sc[j] + sh[j], 0.f);
            acc[j] += f;
        }
    }
    mu16x4 o0, o1;
#pragma unroll
    for (int j = 0; j < 4; j++) o0[j] = f2bf(acc[j]);
#pragma unroll
    for (int j = 0; j < 4; j++) o1[j] = f2bf(acc[4 + j]);
    *(mu16x4*)(z + (size_t)node * HD + c0) = o0;
    *(mu16x4*)(z + (size_t)node * HD + c0 + 4) = o1;
}

// ---------------------------------------------------------------------------
// pooled[g] = sum over graph rows of BN+ReLU(y); then out[g] = pooled @ pw + pb
// ---------------------------------------------------------------------------
__global__ __launch_bounds__(256) void poolfinal_kernel(
    const unsigned short* __restrict__ y, const int* __restrict__ start,
    const float* __restrict__ stats, const float* __restrict__ gamma,
    const float* __restrict__ beta, const float* __restrict__ pw,
    const float* __restrict__ pb, float* __restrict__ out)
{
    __shared__ float red[16][128];
    __shared__ float pl[128];
    __shared__ float sarr[256];
    sarr[threadIdx.x] = fold_stat(stats, threadIdx.x);
    __syncthreads();
    const int g = blockIdx.x;
    const int rg = threadIdx.x >> 4;
    const int c0 = (threadIdx.x & 15) * 8;
    float sc[8], sh[8];
#pragma unroll
    for (int j = 0; j < 8; j++) bn_ss(sarr, gamma, beta, c0 + j, sc[j], sh[j]);
    int s = start[g], e = start[g + 1];
    if (s < 0) s = 0;
    if (e > NN) e = NN;
    float acc[8];
#pragma unroll
    for (int j = 0; j < 8; j++) acc[j] = 0.f;
    for (int n = s + rg; n < e; n += 16) {
        mu32x4 v = *(const mu32x4*)(y + (size_t)n * HD + c0);
        const unsigned short* u = (const unsigned short*)&v;
#pragma unroll
        for (int j = 0; j < 8; j++)
            acc[j] += fmaxf(bf2f(u[j]) * sc[j] + sh[j], 0.f);
    }
#pragma unroll
    for (int j = 0; j < 8; j++) red[rg][c0 + j] = acc[j];
    __syncthreads();
    if (threadIdx.x < 128) {
        float a = 0.f;
#pragma unroll
        for (int k = 0; k < 16; k++) a += red[k][threadIdx.x];
        pl[threadIdx.x] = a;
    }
    __syncthreads();
    const int o = threadIdx.x;
    float facc = pb[o];
#pragma unroll 4
    for (int k = 0; k < 128; k++) facc += pl[k] * pw[k * 256 + o];
    out[(size_t)g * 256 + o] = facc;
}

// ---------------------------------------------------------------------------
extern "C" void kernel_launch(void* const* d_in, const int* in_sizes, int n_in,
                              void* d_out, int out_size, void* d_ws, size_t ws_size,
                              hipStream_t stream)
{
    const float* x      = (const float*)d_in[0];
    const int*   edge   = (const int*)d_in[1];
    const int*   batch  = (const int*)d_in[2];
    const float* emb_W  = (const float*)d_in[4];
    const float* emb_b  = (const float*)d_in[5];
    const float* W1     = (const float*)d_in[6];
    const float* b1     = (const float*)d_in[7];
    const float* g1     = (const float*)d_in[8];
    const float* be1    = (const float*)d_in[9];
    const float* W2     = (const float*)d_in[10];
    const float* b2     = (const float*)d_in[11];
    const float* g2     = (const float*)d_in[12];
    const float* be2    = (const float*)d_in[13];
    const float* eps    = (const float*)d_in[14];
    const float* proj_W = (const float*)d_in[15];
    const float* proj_b = (const float*)d_in[16];
    float* out = (float*)d_out;

    char* ws = (char*)d_ws;
    size_t off = 0;
    auto take = [&](size_t bytes) -> char* {
        char* p = ws + off;
        off += (bytes + 255) & ~(size_t)255;
        return p;
    };
    float*          stats  = (float*)take(6 * SREG * 4);   // 196 KB
    int*            start  = (int*)take((NG + 1) * 4);
    int*            deg    = (int*)take(NN * 4);
    int*            rowptr = (int*)take((NN + 1) * 4);
    int*            cursor = (int*)take(NN * 4);
    int*            bsum   = (int*)take(256 * 4);
    unsigned short* wt     = (unsigned short*)take((size_t)(8192 + 6 * 16384) * 2);
    int*            adj    = (int*)take((size_t)NE * 4);
    unsigned short* zbuf   = (unsigned short*)take((size_t)NN * HD * 2);
    unsigned short* y1buf  = (unsigned short*)take((size_t)NN * HD * 2);
    unsigned short* y2buf  = (unsigned short*)take((size_t)NN * HD * 2);

    const int gemm_grid = (NN + 63) / 64;  // 782
    auto st = [&](int r) { return stats + (size_t)r * SREG; };

    prew_kernel<<<(8192 + 6 * 16384 + 255) / 256, 256, 0, stream>>>(
        emb_W, W1, W2, wt, stats, deg);
    deg_kernel<<<FILLB, 256, 0, stream>>>(edge, deg);
    bscan_kernel<<<NB, 256, 0, stream>>>(deg, rowptr, bsum);
    scanfix_kernel<<<NB, 256, 0, stream>>>(bsum, rowptr, cursor);

    // packed: CSR fill (586 blocks) || embed GEMM (782 blocks)
    gemm_kernel<AD, 0, false, 1><<<FILLB + gemm_grid, 256, 0, stream>>>(
        x, wt, emb_b, nullptr, nullptr, nullptr, y2buf, nullptr, NN,
        edge, cursor, adj);

    for (int l = 0; l < 3; l++) {
        if (l == 0)
            gather_kernel<false><<<(NN + 15) / 16, 256, 0, stream>>>(
                y2buf, rowptr, adj, nullptr, nullptr, nullptr, eps, l, zbuf);
        else
            gather_kernel<true><<<(NN + 15) / 16, 256, 0, stream>>>(
                y2buf, rowptr, adj, st(2 * l - 1),
                g2 + (l - 1) * HD, be2 + (l - 1) * HD, eps, l, zbuf);
        gemm_kernel<HD, 1, true, 0><<<gemm_grid, 256, 0, stream>>>(
            zbuf, wt + 8192 + (size_t)l * 16384, b1 + l * HD,
            nullptr, nullptr, nullptr, y1buf, st(2 * l), NN,
            nullptr, nullptr, nullptr);
        if (l < 2)
            gemm_kernel<HD, 2, true, 0><<<gemm_grid, 256, 0, stream>>>(
                y1buf, wt + 8192 + (size_t)(3 + l) * 16384, b2 + l * HD,
                st(2 * l), g1 + l * HD, be1 + l * HD, y2buf, st(2 * l + 1), NN,
                nullptr, nullptr, nullptr);
        else
            // packed: graph starts (196 blocks) || last GEMM2 (782 blocks)
            gemm_kernel<HD, 2, true, 2><<<NB + gemm_grid, 256, 0, stream>>>(
                y1buf, wt + 8192 + (size_t)(3 + l) * 16384, b2 + l * HD,
                st(2 * l), g1 + l * HD, be1 + l * HD, y2buf, st(2 * l + 1), NN,
                batch, start, nullptr);
    }

    poolfinal_kernel<<<NG, 256, 0, stream>>>(
        y2buf, start, st(5), g2 + 2 * HD, be2 + 2 * HD, proj_W, proj_b, out);
}

// Round 13
// 404.286 us; speedup vs baseline: 1.4249x; 1.0522x over previous
//
#include <hip/hip_runtime.h>
#include <stdint.h>

#define NN 50000   // nodes
#define NE 600000  // edges
#define NG 1000    // graphs
#define AD 64      // input feat
#define HD 128     // hidden
#define OD 256     // output
#define BN_EPS_F 1e-5f
#define INV_N (1.0f / 50000.0f)
#define NB 196     // scan blocks = ceil(NN/256)
#define FILLB 586  // fill tail blocks (4 edges/thread)
#define PREWB 416  // prew main blocks (wt convert = 106496 threads)
#define NCOPY 32   // stats spread copies (256 floats each)
#define SREG (NCOPY * 256)  // floats per stat region

typedef __attribute__((ext_vector_type(8))) short  mbf16x8;
typedef __attribute__((ext_vector_type(4))) float  mf32x4;
typedef __attribute__((ext_vector_type(4))) unsigned short mu16x4;
typedef __attribute__((ext_vector_type(4))) unsigned int   mu32x4;

__device__ __forceinline__ float bf2f(unsigned short u) {
    union { unsigned int i; float f; } v; v.i = ((unsigned int)u) << 16; return v.f;
}
__device__ __forceinline__ unsigned short f2bf(float f) {
    union { float f; unsigned int i; } v; v.f = f;
    unsigned int r = v.i + 0x7fffu + ((v.i >> 16) & 1u);  // RNE
    return (unsigned short)(r >> 16);
}
// BN (scale, shift) for column c from folded raw sums
__device__ __forceinline__ void bn_ss(
    const float* stats, const float* __restrict__ gamma,
    const float* __restrict__ beta, int c, float& sc, float& sh)
{
    const float mean = stats[c] * INV_N;
    const float var = fmaxf(stats[128 + c] * INV_N - mean * mean, 0.f);
    const float inv = rsqrtf(var + BN_EPS_F);
    sc = gamma[c] * inv;
    sh = beta[c] - mean * sc;
}
// fold 32 spread copies of stat index t (t < 256) from a region
__device__ __forceinline__ float fold_stat(const float* __restrict__ reg, int t)
{
    float a = 0.f;
#pragma unroll
    for (int c = 0; c < NCOPY; c++) a += reg[c * 256 + t];
    return a;
}

// ---------------------------------------------------------------------------
// prew: wt[n][k] bf16 from W[k][n] fp32 (PREWB blocks) + zero stats.
// Tail blocks (FILLB): degree histogram (4 edges/thread). deg pre-zeroed
// by memset.
// ---------------------------------------------------------------------------
__global__ __launch_bounds__(256) void prew_kernel(
    const float* __restrict__ emb_W, const float* __restrict__ W1,
    const float* __restrict__ W2, unsigned short* __restrict__ wt,
    float* __restrict__ stats, const int* __restrict__ ei,
    int* __restrict__ deg)
{
    if ((int)blockIdx.x >= PREWB) {
        const int e0 = ((blockIdx.x - PREWB) * 256 + threadIdx.x) * 4;
        if (e0 < NE) {   // NE % 4 == 0
            const int4 rv = *(const int4*)(ei + e0);
            if ((unsigned)rv.x < NN) atomicAdd(&deg[rv.x], 1);
            if ((unsigned)rv.y < NN) atomicAdd(&deg[rv.y], 1);
            if ((unsigned)rv.z < NN) atomicAdd(&deg[rv.z], 1);
            if ((unsigned)rv.w < NN) atomicAdd(&deg[rv.w], 1);
        }
        return;
    }
    const int t = blockIdx.x * 256 + threadIdx.x;
    if (t < 6 * SREG) stats[t] = 0.f;
    if (t < 8192) {                    // emb: n=t>>6, k=t&63
        wt[t] = f2bf(emb_W[(t & 63) * 128 + (t >> 6)]);
    } else {
        const int t2 = t - 8192;
        if (t2 >= 6 * 16384) return;
        const int which = t2 >> 14, o = t2 & 16383;
        const int n = o >> 7, k = o & 127;
        const float* src = (which < 3) ? (W1 + (size_t)which * 16384)
                                       : (W2 + (size_t)(which - 3) * 16384);
        wt[t] = f2bf(src[k * 128 + n]);
    }
}

// ---------------------------------------------------------------------------
// GEMM: out_bf16[N,128] = A[N,K] @ Wt^T + bias   (B direct from global)
// RG = row-groups per wave: tile rows = RG*64. RG=2 shares each B-fragment
// load across 2 row-groups (halves B traffic, doubles MFMA per block).
// AMODE: 0 = A fp32, 1 = A bf16 plain, 2 = A bf16 with BN(stats_in)+ReLU
// SOUT:  per-column sum/sumsq -> spread copy (bid&31); consumers fold.
// TAIL:  1 = CSR fill tail blocks, 2 = graph-starts tail blocks
// ---------------------------------------------------------------------------
template <int K, int RG, int AMODE, bool SOUT, int TAIL>
__global__ __launch_bounds__(256) void gemm_kernel(
    const void* __restrict__ in, const unsigned short* __restrict__ Wt,
    const float* __restrict__ bias, const float* __restrict__ stats_in,
    const float* __restrict__ gamma, const float* __restrict__ beta,
    unsigned short* __restrict__ out, float* __restrict__ stats_out, int n_rows,
    const int* __restrict__ t_a, int* __restrict__ t_b, int* __restrict__ t_c)
{
    constexpr int TAILB = (TAIL == 1) ? FILLB : (TAIL == 2) ? NB : 0;
    if (TAIL != 0 && (int)blockIdx.x < TAILB) {
        const int t = blockIdx.x * 256 + threadIdx.x;
        if constexpr (TAIL == 1) {
            const int e0 = t * 4;
            if (e0 < NE) {   // NE % 4 == 0
                const int4 rv = *(const int4*)(t_a + e0);
                const int4 cv = *(const int4*)(t_a + NE + e0);
                if ((unsigned)rv.x < NN && (unsigned)cv.x < NN)
                    t_c[atomicAdd(&t_b[rv.x], 1)] = cv.x;
                if ((unsigned)rv.y < NN && (unsigned)cv.y < NN)
                    t_c[atomicAdd(&t_b[rv.y], 1)] = cv.y;
                if ((unsigned)rv.z < NN && (unsigned)cv.z < NN)
                    t_c[atomicAdd(&t_b[rv.z], 1)] = cv.z;
                if ((unsigned)rv.w < NN && (unsigned)cv.w < NN)
                    t_c[atomicAdd(&t_b[rv.w], 1)] = cv.w;
            }
        } else {  // TAIL == 2: graph starts
            if (t < NN) {
                int b = t_a[t];
                int pb = (t == 0) ? -1 : t_a[t - 1];
                if (b > NG - 1) b = NG - 1;
                if (pb > NG - 1) pb = NG - 1;
                for (int g = pb + 1; g <= b; g++) t_b[g] = t;
                if (t == NN - 1)
                    for (int g = b + 1; g <= NG; g++) t_b[g] = NN;
            }
        }
        return;
    }
    const int bid = blockIdx.x - TAILB;

    constexpr int ROWS = RG * 64;
    constexpr int SA = K + 8;
    __shared__ unsigned short zs[ROWS * SA];
    __shared__ float ssl[128], ssh[128];
    __shared__ float lsum[128], lsq[128];
    __shared__ float sarr[256];

    const int tid = threadIdx.x;
    const int wave = tid >> 6, lane = tid & 63;
    const int row0 = bid * ROWS;

    if (SOUT && tid < 128) { lsum[tid] = 0.f; lsq[tid] = 0.f; }
    if (AMODE == 2) {
        sarr[tid] = fold_stat(stats_in, tid);
        __syncthreads();
        if (tid < 128) {
            float sc, sh; bn_ss(sarr, gamma, beta, tid, sc, sh);
            ssl[tid] = sc; ssh[tid] = sh;
        }
        __syncthreads();
    }

    // ---- stage A tile -> LDS ----
    if constexpr (AMODE == 0) {
        const float* src = (const float*)in;
        constexpr int LPR = K / 4;
        for (int i = tid; i < ROWS * LPR; i += 256) {
            const int r = i / LPR, c4 = (i % LPR) * 4;
            mf32x4 v = {0.f, 0.f, 0.f, 0.f};
            if (row0 + r < n_rows)
                v = *(const mf32x4*)(src + (size_t)(row0 + r) * K + c4);
            mu16x4 o;
            o[0] = f2bf(v[0]); o[1] = f2bf(v[1]); o[2] = f2bf(v[2]); o[3] = f2bf(v[3]);
            *(mu16x4*)(&zs[r * SA + c4]) = o;
        }
    } else {
        const unsigned short* src = (const unsigned short*)in;
        constexpr int LPR = K / 8;
        float sc[8], sh[8];
        if constexpr (AMODE == 2) {
            const int c8 = (tid % LPR) * 8;   // fixed per thread (256 % LPR == 0)
#pragma unroll
            for (int j = 0; j < 8; j++) { sc[j] = ssl[c8 + j]; sh[j] = ssh[c8 + j]; }
        }
        for (int i = tid; i < ROWS * LPR; i += 256) {
            const int r = i / LPR, c8 = (i % LPR) * 8;
            mu32x4 v = {0, 0, 0, 0};
            if (row0 + r < n_rows)
                v = *(const mu32x4*)(src + (size_t)(row0 + r) * K + c8);
            if constexpr (AMODE == 2) {
                const unsigned short* u = (const unsigned short*)&v;
                mu16x4 oa, ob;
#pragma unroll
                for (int j = 0; j < 4; j++)
                    oa[j] = f2bf(fmaxf(bf2f(u[j]) * sc[j] + sh[j], 0.f));
#pragma unroll
                for (int j = 0; j < 4; j++)
                    ob[j] = f2bf(fmaxf(bf2f(u[4 + j]) * sc[4 + j] + sh[4 + j], 0.f));
                *(mu16x4*)(&zs[r * SA + c8]) = oa;
                *(mu16x4*)(&zs[r * SA + c8 + 4]) = ob;
            } else {
                *(mu32x4*)(&zs[r * SA + c8]) = v;
            }
        }
    }
    __syncthreads();

    // ---- MFMA: B-frags direct from global, shared across RG row-groups ----
    mf32x4 acc[RG][8];
#pragma unroll
    for (int g = 0; g < RG; g++)
#pragma unroll
        for (int t = 0; t < 8; t++) acc[g][t] = {0.f, 0.f, 0.f, 0.f};
    const int kq = (lane >> 4) * 8;
    int mrow[RG];
#pragma unroll
    for (int g = 0; g < RG; g++) mrow[g] = wave * (16 * RG) + g * 16 + (lane & 15);
    const unsigned short* wn = Wt + (lane & 15) * K;  // + t*16*K + k0
#pragma unroll 1
    for (int kk = 0; kk < K / 32; kk++) {
        const int k0 = kk * 32 + kq;
        mbf16x8 a[RG];
#pragma unroll
        for (int g = 0; g < RG; g++) a[g] = *(const mbf16x8*)(&zs[mrow[g] * SA + k0]);
        mbf16x8 bfr[8];
#pragma unroll
        for (int t = 0; t < 8; t++) bfr[t] = *(const mbf16x8*)(wn + t * 16 * K + k0);
#pragma unroll
        for (int t = 0; t < 8; t++)
#pragma unroll
            for (int g = 0; g < RG; g++)
                acc[g][t] = __builtin_amdgcn_mfma_f32_16x16x32_bf16(
                    a[g], bfr[t], acc[g][t], 0, 0, 0);
    }

    // ---- epilogue: +bias, store bf16; stats -> spread copy (bid&31) ----
#pragma unroll
    for (int g = 0; g < RG; g++) {
        const int rbase = wave * (16 * RG) + g * 16 + ((lane >> 4) << 2);
#pragma unroll
        for (int t = 0; t < 8; t++) {
            const int c = t * 16 + (lane & 15);
            const float bv = bias[c];
            float s = 0.f, q = 0.f;
#pragma unroll
            for (int r = 0; r < 4; r++) {
                const int grow = row0 + rbase + r;
                const float y = acc[g][t][r] + bv;
                if (grow < n_rows) {
                    out[(size_t)grow * 128 + c] = f2bf(y);
                    if (SOUT) { s += y; q += y * y; }
                }
            }
            if (SOUT) {
                s += __shfl_xor(s, 16); s += __shfl_xor(s, 32);
                q += __shfl_xor(q, 16); q += __shfl_xor(q, 32);
                if ((lane >> 4) == 0) {
                    atomicAdd(&lsum[c], s);
                    atomicAdd(&lsq[c], q);
                }
            }
        }
    }
    if (SOUT) {
        __syncthreads();
        float* cb = stats_out + (bid & (NCOPY - 1)) * 256;
        if (tid < 128) {
            atomicAdd(&cb[tid], lsum[tid]);
            atomicAdd(&cb[128 + tid], lsq[tid]);
        }
    }
}

// ---------------------------------------------------------------------------
// CSR build: bscan -> scanfix  (deg done in prew tail)
// ---------------------------------------------------------------------------
__global__ __launch_bounds__(256) void bscan_kernel(
    const int* __restrict__ deg, int* __restrict__ rowptr, int* __restrict__ bsum)
{
    __shared__ int sm[256];
    const int t = threadIdx.x, idx = blockIdx.x * 256 + t;
    const int d = (idx < NN) ? deg[idx] : 0;
    sm[t] = d; __syncthreads();
    for (int ofs = 1; ofs < 256; ofs <<= 1) {
        int v = (t >= ofs) ? sm[t - ofs] : 0;
        __syncthreads();
        sm[t] += v;
        __syncthreads();
    }
    if (idx < NN) rowptr[idx] = sm[t] - d;  // exclusive, block-local
    if (t == 255) bsum[blockIdx.x] = sm[255];
}

__global__ __launch_bounds__(256) void scanfix_kernel(
    const int* __restrict__ bsum, int* __restrict__ rowptr, int* __restrict__ cursor)
{
    __shared__ int sm[256];
    const int t = threadIdx.x;
    const int d = (t < NB) ? bsum[t] : 0;
    sm[t] = d; __syncthreads();
    for (int ofs = 1; ofs < 256; ofs <<= 1) {
        int v = (t >= ofs) ? sm[t - ofs] : 0;
        __syncthreads();
        sm[t] += v;
        __syncthreads();
    }
    const int boff = (blockIdx.x == 0) ? 0 : sm[blockIdx.x - 1];
    const int idx = blockIdx.x * 256 + t;
    if (idx < NN) {
        const int v = rowptr[idx] + boff;
        rowptr[idx] = v;
        cursor[idx] = v;
    }
    if (blockIdx.x == NB - 1 && t == 0) rowptr[NN] = sm[NB - 1];
}

// ---------------------------------------------------------------------------
// gather: z[n] = (1+eps[l])*f(src[n]) + sum_{c in adj[n]} f(src[c])
// ---------------------------------------------------------------------------
template <bool BN>
__global__ __launch_bounds__(256) void gather_kernel(
    const unsigned short* __restrict__ src, const int* __restrict__ rowptr,
    const int* __restrict__ adj, const float* __restrict__ stats,
    const float* __restrict__ gamma, const float* __restrict__ beta,
    const float* __restrict__ eps, int l, unsigned short* __restrict__ z)
{
    __shared__ float sarr[256];
    if constexpr (BN) {
        sarr[threadIdx.x] = fold_stat(stats, threadIdx.x);
        __syncthreads();
    }
    const int node = blockIdx.x * 16 + (threadIdx.x >> 4);
    const int c0 = (threadIdx.x & 15) * 8;
    if (node >= NN) return;
    float sc[8], sh[8];
    if (BN) {
#pragma unroll
        for (int j = 0; j < 8; j++) bn_ss(sarr, gamma, beta, c0 + j, sc[j], sh[j]);
    }
    const float e = 1.0f + eps[l];
    float acc[8];
    {
        mu32x4 v = *(const mu32x4*)(src + (size_t)node * HD + c0);
        const unsigned short* u = (const unsigned short*)&v;
#pragma unroll
        for (int j = 0; j < 8; j++) {
            float f = bf2f(u[j]);
            if (BN) f = fmaxf(f * sc[j] + sh[j], 0.f);
            acc[j] = e * f;
        }
    }
    const int s = rowptr[node], t = rowptr[node + 1];
    int i = s;
    for (; i + 4 <= t; i += 4) {
        const int n0 = adj[i], n1 = adj[i + 1], n2 = adj[i + 2], n3 = adj[i + 3];
        mu32x4 v0 = *(const mu32x4*)(src + (size_t)n0 * HD + c0);
        mu32x4 v1 = *(const mu32x4*)(src + (size_t)n1 * HD + c0);
        mu32x4 v2 = *(const mu32x4*)(src + (size_t)n2 * HD + c0);
        mu32x4 v3 = *(const mu32x4*)(src + (size_t)n3 * HD + c0);
        const unsigned short* u0 = (const unsigned short*)&v0;
        const unsigned short* u1 = (const unsigned short*)&v1;
        const unsigned short* u2 = (const unsigned short*)&v2;
        const unsigned short* u3 = (const unsigned short*)&v3;
#pragma unroll
        for (int j = 0; j < 8; j++) {
            float f0 = bf2f(u0[j]), f1 = bf2f(u1[j]);
            float f2 = bf2f(u2[j]), f3 = bf2f(u3[j]);
            if (BN) {
                f0 = fmaxf(f0 * sc[j] + sh[j], 0.f);
                f1 = fmaxf(f1 * sc[j] + sh[j], 0.f);
                f2 = fmaxf(f2 * sc[j] + sh[j], 0.f);
                f3 = fmaxf(f3 * sc[j] + sh[j], 0.f);
            }
            acc[j] += (f0 + f1) + (f2 + f3);
        }
    }
    for (; i < t; i++) {
        mu32x4 v = *(const mu32x4*)(src + (size_t)adj[i] * HD + c0);
        const unsigned short* u = (const unsigned short*)&v;
#pragma unroll
        for (int j = 0; j < 8; j++) {
            float f = bf2f(u[j]);
            if (BN) f = fmaxf(f * sc[j] + sh[j], 0.f);
            acc[j] += f;
        }
    }
    mu16x4 o0, o1;
#pragma unroll
    for (int j = 0; j < 4; j++) o0[j] = f2bf(acc[j]);
#pragma unroll
    for (int j = 0; j < 4; j++) o1[j] = f2bf(acc[4 + j]);
    *(mu16x4*)(z + (size_t)node * HD + c0) = o0;
    *(mu16x4*)(z + (size_t)node * HD + c0 + 4) = o1;
}

// ---------------------------------------------------------------------------
// pooled[g] = sum over graph rows of BN+ReLU(y); then out[g] = pooled @ pw + pb
// ---------------------------------------------------------------------------
__global__ __launch_bounds__(256) void poolfinal_kernel(
    const unsigned short* __restrict__ y, const int* __restrict__ start,
    const float* __restrict__ stats, const float* __restrict__ gamma,
    const float* __restrict__ beta, const float* __restrict__ pw,
    const float* __restrict__ pb, float* __restrict__ out)
{
    __shared__ float red[16][128];
    __shared__ float pl[128];
    __shared__ float sarr[256];
    sarr[threadIdx.x] = fold_stat(stats, threadIdx.x);
    __syncthreads();
    const int g = blockIdx.x;
    const int rg = threadIdx.x >> 4;
    const int c0 = (threadIdx.x & 15) * 8;
    float sc[8], sh[8];
#pragma unroll
    for (int j = 0; j < 8; j++) bn_ss(sarr, gamma, beta, c0 + j, sc[j], sh[j]);
    int s = start[g], e = start[g + 1];
    if (s < 0) s = 0;
    if (e > NN) e = NN;
    float acc[8];
#pragma unroll
    for (int j = 0; j < 8; j++) acc[j] = 0.f;
    for (int n = s + rg; n < e; n += 16) {
        mu32x4 v = *(const mu32x4*)(y + (size_t)n * HD + c0);
        const unsigned short* u = (const unsigned short*)&v;
#pragma unroll
        for (int j = 0; j < 8; j++)
            acc[j] += fmaxf(bf2f(u[j]) * sc[j] + sh[j], 0.f);
    }
#pragma unroll
    for (int j = 0; j < 8; j++) red[rg][c0 + j] = acc[j];
    __syncthreads();
    if (threadIdx.x < 128) {
        float a = 0.f;
#pragma unroll
        for (int k = 0; k < 16; k++) a += red[k][threadIdx.x];
        pl[threadIdx.x] = a;
    }
    __syncthreads();
    const int o = threadIdx.x;
    float facc = pb[o];
#pragma unroll 4
    for (int k = 0; k < 128; k++) facc += pl[k] * pw[k * 256 + o];
    out[(size_t)g * 256 + o] = facc;
}

// ---------------------------------------------------------------------------
extern "C" void kernel_launch(void* const* d_in, const int* in_sizes, int n_in,
                              void* d_out, int out_size, void* d_ws, size_t ws_size,
                              hipStream_t stream)
{
    const float* x      = (const float*)d_in[0];
    const int*   edge   = (const int*)d_in[1];
    const int*   batch  = (const int*)d_in[2];
    const float* emb_W  = (const float*)d_in[4];
    const float* emb_b  = (const float*)d_in[5];
    const float* W1     = (const float*)d_in[6];
    const float* b1     = (const float*)d_in[7];
    const float* g1     = (const float*)d_in[8];
    const float* be1    = (const float*)d_in[9];
    const float* W2     = (const float*)d_in[10];
    const float* b2     = (const float*)d_in[11];
    const float* g2     = (const float*)d_in[12];
    const float* be2    = (const float*)d_in[13];
    const float* eps    = (const float*)d_in[14];
    const float* proj_W = (const float*)d_in[15];
    const float* proj_b = (const float*)d_in[16];
    float* out = (float*)d_out;

    char* ws = (char*)d_ws;
    size_t off = 0;
    auto take = [&](size_t bytes) -> char* {
        char* p = ws + off;
        off += (bytes + 255) & ~(size_t)255;
        return p;
    };
    float*          stats  = (float*)take(6 * SREG * 4);   // 196 KB
    int*            start  = (int*)take((NG + 1) * 4);
    int*            deg    = (int*)take(NN * 4);
    int*            rowptr = (int*)take((NN + 1) * 4);
    int*            cursor = (int*)take(NN * 4);
    int*            bsum   = (int*)take(256 * 4);
    unsigned short* wt     = (unsigned short*)take((size_t)(8192 + 6 * 16384) * 2);
    int*            adj    = (int*)take((size_t)NE * 4);
    unsigned short* zbuf   = (unsigned short*)take((size_t)NN * HD * 2);
    unsigned short* y1buf  = (unsigned short*)take((size_t)NN * HD * 2);
    unsigned short* y2buf  = (unsigned short*)take((size_t)NN * HD * 2);

    const int eg_grid = (NN + 63) / 64;    // 782 (embed, RG=1)
    const int lg_grid = (NN + 127) / 128;  // 391 (layer GEMMs, RG=2)
    auto st = [&](int r) { return stats + (size_t)r * SREG; };

    hipMemsetAsync(deg, 0, NN * 4, stream);
    // packed: wt convert + stats zero (416 blocks) || degree histogram (586)
    prew_kernel<<<PREWB + FILLB, 256, 0, stream>>>(
        emb_W, W1, W2, wt, stats, edge, deg);
    bscan_kernel<<<NB, 256, 0, stream>>>(deg, rowptr, bsum);
    scanfix_kernel<<<NB, 256, 0, stream>>>(bsum, rowptr, cursor);

    // packed: CSR fill (586 blocks) || embed GEMM (782 blocks, RG=1)
    gemm_kernel<AD, 1, 0, false, 1><<<FILLB + eg_grid, 256, 0, stream>>>(
        x, wt, emb_b, nullptr, nullptr, nullptr, y2buf, nullptr, NN,
        edge, cursor, adj);

    for (int l = 0; l < 3; l++) {
        if (l == 0)
            gather_kernel<false><<<(NN + 15) / 16, 256, 0, stream>>>(
                y2buf, rowptr, adj, nullptr, nullptr, nullptr, eps, l, zbuf);
        else
            gather_kernel<true><<<(NN + 15) / 16, 256, 0, stream>>>(
                y2buf, rowptr, adj, st(2 * l - 1),
                g2 + (l - 1) * HD, be2 + (l - 1) * HD, eps, l, zbuf);
        gemm_kernel<HD, 2, 1, true, 0><<<lg_grid, 256, 0, stream>>>(
            zbuf, wt + 8192 + (size_t)l * 16384, b1 + l * HD,
            nullptr, nullptr, nullptr, y1buf, st(2 * l), NN,
            nullptr, nullptr, nullptr);
        if (l < 2)
            gemm_kernel<HD, 2, 2, true, 0><<<lg_grid, 256, 0, stream>>>(
                y1buf, wt + 8192 + (size_t)(3 + l) * 16384, b2 + l * HD,
                st(2 * l), g1 + l * HD, be1 + l * HD, y2buf, st(2 * l + 1), NN,
                nullptr, nullptr, nullptr);
        else
            // packed: graph starts (196 blocks) || last GEMM2 (391 blocks)
            gemm_kernel<HD, 2, 2, true, 2><<<NB + lg_grid, 256, 0, stream>>>(
                y1buf, wt + 8192 + (size_t)(3 + l) * 16384, b2 + l * HD,
                st(2 * l), g1 + l * HD, be1 + l * HD, y2buf, st(2 * l + 1), NN,
                batch, start, nullptr);
    }

    poolfinal_kernel<<<NG, 256, 0, stream>>>(
        y2buf, start, st(5), g2 + 2 * HD, be2 + 2 * HD, proj_W, proj_b, out);
}